// Round 9
// baseline (542.047 us; speedup 1.0000x reference)
//
#include <hip/hip_runtime.h>
#include <stdint.h>

#define EPS 1e-5f

typedef short v8s __attribute__((ext_vector_type(8)));
typedef float v4f __attribute__((ext_vector_type(4)));

// ---------------- ws float layout ----------------
//  [0,4)     absmax {c1,c2,f1,f2}
//  272/400  c2 sum/ssq (128 each)
//  1808 fc sum(512) 2320 fc ssq(512)
//  2832..3183: xcorr C matrix (351 floats, 26x26 upper-tri incl. means row)
//  W1F  = 4096    : conv1 weights float [k=25][c=64]
//  W2F  = 8192    : conv2 weights bf16 MFMA-frag order (204800 us)
//  WF2F = 212992  : fc2 weights float [j][512]
//  A_F  = 262144  : PMN fp32 [512][128][16][2]{max,min}; later fc1out fp32 [512,512]
//  B_F  = 19136512: pool1 bf16 NHWC [512][144][64]; later pool2 bf16 B-frag
//  WF1T = B_F + 1048576 : fc1 weights bf16 A-frag (written after conv2)
static const size_t W1F  = 4096;
static const size_t W2F  = 8192;
static const size_t WF2F = 212992;
static const size_t A_F  = 262144;
static const size_t B_F  = 19136512;
static const size_t WF1T = B_F + 1048576;

__device__ inline unsigned short f2bf(float f) {
    unsigned u = __float_as_uint(f);
    return (unsigned short)((u + 0x7FFF + ((u >> 16) & 1)) >> 16);
}

__global__ void k_zero(float* p, int n) {
    int i = blockIdx.x * blockDim.x + threadIdx.x;
    if (i < n) p[i] = 0.f;
}

// 4 absmax reductions in one launch
__global__ void k_absmax4(const float* __restrict__ w0, int n0,
                          const float* __restrict__ w1, int n1,
                          const float* __restrict__ w2, int n2,
                          const float* __restrict__ w3, int n3,
                          float* outv) {
    int blk = blockIdx.x;
    const float* w; int n; unsigned* out; int nb; int bi;
    if (blk < 1)        { w = w0; n = n0; out = (unsigned*)(outv + 0); nb = 1;   bi = blk;      }
    else if (blk < 17)  { w = w1; n = n1; out = (unsigned*)(outv + 1); nb = 16;  bi = blk - 1;  }
    else if (blk < 209) { w = w2; n = n2; out = (unsigned*)(outv + 2); nb = 192; bi = blk - 17; }
    else                { w = w3; n = n3; out = (unsigned*)(outv + 3); nb = 1;   bi = blk - 209; }
    float m = 0.f;
    for (int i = bi * 256 + threadIdx.x; i < n; i += nb * 256)
        m = fmaxf(m, fabsf(w[i]));
    #pragma unroll
    for (int o = 32; o; o >>= 1) m = fmaxf(m, __shfl_down(m, o));
    if ((threadIdx.x & 63) == 0) atomicMax(out, __float_as_uint(m));
}

// quantize: conv1 -> w1t float [k=25][c=64]; conv2 -> bf16 A-frag (coalesced read,
// scattered write); fc2 float straight.
__global__ void k_quantE(const float* __restrict__ c1w, const float* __restrict__ c2w,
                         const float* __restrict__ f2w, const float* __restrict__ am,
                         float* __restrict__ w1t, unsigned short* __restrict__ w2u,
                         float* __restrict__ wf2) {
    int blk = blockIdx.x;
    if (blk < 1) {
        float t = 0.05f * am[0];
        for (int i = threadIdx.x; i < 1600; i += 256) {
            float v = c1w[i];
            float q = (float)((v > t) - (v < -t));
            int c = i / 25, k = i - c * 25;
            w1t[k * 64 + c] = q;
        }
    } else if (blk < 101) {
        float t = 0.05f * am[1];
        int base = (blk - 1) * 2048;
        #pragma unroll
        for (int jj = 0; jj < 8; ++jj) {
            int i = base + jj * 256 + threadIdx.x;   // linear over c2w: coalesced read
            float v = c2w[i];
            unsigned short q = (v > t) ? (unsigned short)0x3F80
                               : ((v < -t) ? (unsigned short)0xBF80 : (unsigned short)0);
            int c  = i / 1600; int r = i - c * 1600;
            int ci = r / 25;   int p = r - ci * 25;
            int mt = c >> 4, ks = ci >> 5;
            int lane = ((ci >> 3) & 3) * 16 + (c & 15);
            int j = ci & 7;
            w2u[(size_t)((p * 2 + ks) * 8 + mt) * 512 + lane * 8 + j] = q;
        }
    } else {
        float t = 0.05f * am[3];
        for (int i = threadIdx.x; i < 5120; i += 256) {
            float v = f2w[i];
            wf2[i] = (float)((v > t) - (v < -t));
        }
    }
}

// fc1 quantize -> bf16 A-frag (1048576 threads exactly)
__global__ void k_quantF1(const float* __restrict__ w, const float* __restrict__ am,
                          unsigned short* __restrict__ wf) {
    float t = 0.05f * am[2];
    int i = blockIdx.x * 256 + threadIdx.x;
    int j    = i & 7;
    int lane = (i >> 3) & 63;
    int ft   = (i >> 9) & 31;
    int ks   = i >> 14;
    int f = ft * 16 + (lane & 15);
    int k = ks * 32 + (lane >> 4) * 8 + j;
    float v = w[f * 2048 + k];
    wf[i] = (v > t) ? (unsigned short)0x3F80
                    : ((v < -t) ? (unsigned short)0xBF80 : (unsigned short)0);
}

// ---- xcorr: C[t(k,l)] = sum over (b,sp) of win_k * win_l, win[25]=1 (means row)
static const int NPAIR = 351;
struct PTab { unsigned char k[NPAIR]; unsigned char l[NPAIR]; };
constexpr PTab mkPT() {
    PTab p{}; int t = 0;
    for (int a = 0; a < 26; ++a)
        for (int b = a; b < 26; ++b) { p.k[t] = (unsigned char)a; p.l[t] = (unsigned char)b; ++t; }
    return p;
}
constexpr PTab PT = mkPT();

template<int LO, int HI>
__device__ __forceinline__ void xcorr_range(const float* __restrict__ xs, int lane,
                                            float* __restrict__ Cg) {
    float acc[HI - LO];
    #pragma unroll
    for (int t = 0; t < HI - LO; ++t) acc[t] = 0.f;
    for (int it = 0; it < 9; ++it) {
        int sp = it * 64 + lane;
        int oh = sp / 24, ow = sp - oh * 24;
        float win[26];
        #pragma unroll
        for (int kh = 0; kh < 5; ++kh)
            #pragma unroll
            for (int kw = 0; kw < 5; ++kw)
                win[kh * 5 + kw] = xs[(oh + kh) * 28 + ow + kw];
        win[25] = 1.f;
        #pragma unroll
        for (int t = LO; t < HI; ++t)
            acc[t - LO] = fmaf(win[PT.k[t]], win[PT.l[t]], acc[t - LO]);
    }
    #pragma unroll
    for (int t = 0; t < HI - LO; ++t) {
        float r = acc[t];
        #pragma unroll
        for (int o = 32; o; o >>= 1) r += __shfl_down(r, o);
        if (lane == 0) atomicAdd(&Cg[LO + t], r);
    }
}

__global__ __launch_bounds__(384) void k_xcorr(const float* __restrict__ x,
                                               float* __restrict__ Cg) {
    __shared__ float xs[784];
    int b = blockIdx.x;
    const float4* xim = (const float4*)(x + (size_t)b * 784);
    for (int i = threadIdx.x; i < 196; i += 384) ((float4*)xs)[i] = xim[i];
    __syncthreads();
    int w = threadIdx.x >> 6, lane = threadIdx.x & 63;
    switch (w) {
        case 0: xcorr_range<0,   59 >(xs, lane, Cg); break;
        case 1: xcorr_range<59,  118>(xs, lane, Cg); break;
        case 2: xcorr_range<118, 177>(xs, lane, Cg); break;
        case 3: xcorr_range<177, 235>(xs, lane, Cg); break;
        case 4: xcorr_range<235, 293>(xs, lane, Cg); break;
        default: xcorr_range<293, 351>(xs, lane, Cg); break;
    }
}

// conv1B: inline bn1 finalize from C, then conv1+bn+relu+pool -> pool1 NHWC bf16
__global__ __launch_bounds__(512) void k_conv1B(const float* __restrict__ x,
                                                const float* __restrict__ w1t,
                                                const float* __restrict__ Cg,
                                                const float* __restrict__ g1,
                                                const float* __restrict__ b1,
                                                unsigned short* __restrict__ pool1) {
    __shared__ float xs[784];
    __shared__ float scsh[128];
    int b = blockIdx.x;
    const float4* xim = (const float4*)(x + (size_t)b * 784);
    for (int i = threadIdx.x; i < 196; i += 512) ((float4*)xs)[i] = xim[i];
    if (threadIdx.x < 64) {
        int c = threadIdx.x;
        float wq[25];
        #pragma unroll
        for (int k = 0; k < 25; ++k) wq[k] = w1t[k * 64 + c];
        float mean = 0.f, ey2 = 0.f;
        int t = 0;
        for (int k = 0; k < 26; ++k)
            for (int l = k; l < 26; ++l, ++t) {
                if (k == 25) continue;
                float Cv = Cg[t];
                if (l == 25) mean += wq[k] * Cv;
                else ey2 = fmaf(wq[k] * wq[l] * ((k == l) ? 1.f : 2.f), Cv, ey2);
            }
        const float invN = 1.f / 294912.f;
        mean *= invN; ey2 *= invN;
        float var = ey2 - mean * mean;
        float sc = g1[c] * rsqrtf(var + EPS);
        scsh[c] = sc; scsh[64 + c] = b1[c] - mean * sc;
    }
    int c  = threadIdx.x & 63;
    int wv = threadIdx.x >> 6;
    float w[25];
    #pragma unroll
    for (int k = 0; k < 25; ++k) w[k] = w1t[k * 64 + c];
    __syncthreads();
    float sc = scsh[c], sh = scsh[64 + c];
    unsigned short* ob = pool1 + (size_t)b * 9216;
    int ph = 0, pw = wv;
    for (int it = 0; it < 18; ++it) {
        const float* xp = xs + (ph * 2) * 28 + pw * 2;
        float win[36];
        #pragma unroll
        for (int i = 0; i < 6; ++i)
            #pragma unroll
            for (int j = 0; j < 3; ++j) {
                float2 t2 = *(const float2*)(xp + i * 28 + j * 2);
                win[i * 6 + j * 2] = t2.x; win[i * 6 + j * 2 + 1] = t2.y;
            }
        float v00 = 0.f, v01 = 0.f, v10 = 0.f, v11 = 0.f;
        #pragma unroll
        for (int i = 0; i < 5; ++i)
            #pragma unroll
            for (int j = 0; j < 5; ++j) {
                float wk = w[i * 5 + j];
                v00 = fmaf(win[i * 6 + j],           wk, v00);
                v01 = fmaf(win[i * 6 + j + 1],       wk, v01);
                v10 = fmaf(win[(i + 1) * 6 + j],     wk, v10);
                v11 = fmaf(win[(i + 1) * 6 + j + 1], wk, v11);
            }
        float r0 = fmaxf(0.f, fmaf(v00, sc, sh));
        float r1 = fmaxf(0.f, fmaf(v01, sc, sh));
        float r2 = fmaxf(0.f, fmaf(v10, sc, sh));
        float r3 = fmaxf(0.f, fmaf(v11, sc, sh));
        ob[(ph * 12 + pw) * 64 + c] = f2bf(fmaxf(fmaxf(r0, r1), fmaxf(r2, r3)));
        pw += 8; if (pw >= 12) { pw -= 12; ++ph; }
    }
}

// conv2 MFMA v5: grid 1024 = (image, sp-half); 4 blocks/CU. Wave = M=32 x N=32.
// Weights direct global->VGPR, depth-3 prefetch; one barrier; fused stats + pool.
__global__ __launch_bounds__(256) void k_conv2(const unsigned short* __restrict__ pool1,
                                               const unsigned short* __restrict__ wfrag,
                                               float* __restrict__ pmn,
                                               float* __restrict__ sum,
                                               float* __restrict__ ssq) {
    __shared__ unsigned short xs[96 * 72];     // 8 rows x 12 cols x 64ci, pad 72
    int b   = blockIdx.x >> 1;
    int sh2 = blockIdx.x & 1;
    int tid = threadIdx.x;
    int lane = tid & 63;
    int w = tid >> 6;
    const unsigned short* src = pool1 + (size_t)b * 9216 + sh2 * 3072;  // r0=sh2*4 rows
    for (int i = tid; i < 768; i += 256) {
        int rc = i >> 3, part = i & 7;
        *(float4*)(&xs[rc * 72 + part * 8]) = *(const float4*)(src + rc * 64 + part * 8);
    }
    int n = lane & 15, quad = lane >> 4;
    const unsigned short* wbase = wfrag + (size_t)(w * 2) * 512 + lane * 8;
    v8s pf[4][2];
    #pragma unroll
    for (int s = 0; s < 3; ++s) {
        pf[s][0] = *(const v8s*)(wbase + (size_t)(s * 8) * 512);
        pf[s][1] = *(const v8s*)(wbase + (size_t)(s * 8 + 1) * 512);
    }
    __syncthreads();
    v4f acc[2][2];
    #pragma unroll
    for (int mm = 0; mm < 2; ++mm) { acc[mm][0] = (v4f){0,0,0,0}; acc[mm][1] = (v4f){0,0,0,0}; }
    int ow = n & 7, ohl = n >> 3;
    #pragma unroll
    for (int step = 0; step < 50; ++step) {
        if (step + 3 < 50) {
            pf[(step + 3) & 3][0] = *(const v8s*)(wbase + (size_t)((step + 3) * 8) * 512);
            pf[(step + 3) & 3][1] = *(const v8s*)(wbase + (size_t)((step + 3) * 8 + 1) * 512);
        }
        int p = step >> 1, ks = step & 1;
        int kh = p / 5, kw = p - kh * 5;
        #pragma unroll
        for (int q = 0; q < 2; ++q) {
            int rr = q * 2 + ohl + kh;         // 0..7
            v8s bf = *(const v8s*)(&xs[(rr * 12 + ow + kw) * 72 + ks * 32 + quad * 8]);
            acc[0][q] = __builtin_amdgcn_mfma_f32_16x16x32_bf16(pf[step & 3][0], bf, acc[0][q], 0, 0, 0);
            acc[1][q] = __builtin_amdgcn_mfma_f32_16x16x32_bf16(pf[step & 3][1], bf, acc[1][q], 0, 0, 0);
        }
    }
    float* po = pmn + (size_t)b * 4096;        // [128][16][2]
    #pragma unroll
    for (int mm = 0; mm < 2; ++mm) {
        #pragma unroll
        for (int r = 0; r < 4; ++r) {
            int c = w * 32 + mm * 16 + quad * 4 + r;
            float sA = 0.f, s2A = 0.f;
            #pragma unroll
            for (int q = 0; q < 2; ++q) {
                float v = acc[mm][q][r];
                float pm = fmaxf(v, __shfl_xor(v, 1));
                float pn = fminf(v, __shfl_xor(v, 1));
                pm = fmaxf(pm, __shfl_xor(pm, 8));
                pn = fminf(pn, __shfl_xor(pn, 8));
                if (((n & 1) == 0) && (n < 8)) {
                    int psp = (sh2 * 2 + q) * 4 + (n >> 1);
                    *(float2*)(&po[(c * 16 + psp) * 2]) = make_float2(pm, pn);
                }
                float s = v, s2 = v * v;
                #pragma unroll
                for (int m = 1; m < 16; m <<= 1) { s += __shfl_xor(s, m); s2 += __shfl_xor(s2, m); }
                sA += s; s2A += s2;
            }
            if (n == 0) { atomicAdd(&sum[c], sA); atomicAdd(&ssq[c], s2A); }
        }
    }
}

// bn2 finalize inline + relu on pooled pairs -> pool2 bf16 in fc1 B-frag order
__global__ void k_bnpool2(const float* __restrict__ pmn, const float* __restrict__ c2sum,
                          const float* __restrict__ c2ssq, const float* __restrict__ g2,
                          const float* __restrict__ b2, unsigned short* __restrict__ xfrag) {
    int i = blockIdx.x * 256 + threadIdx.x;    // 1048576
    int j    = i & 7;
    int lane = (i >> 3) & 63;
    int bt   = (i >> 9) & 31;
    int ks   = i >> 14;
    int b = bt * 16 + (lane & 15);
    int k = ks * 32 + (lane >> 4) * 8 + j;
    int c = k >> 4, psp = k & 15;
    float2 mm = *(const float2*)(&pmn[((size_t)b * 2048 + c * 16 + psp) * 2]);
    float mean = c2sum[c] * (1.f / 32768.f);
    float var  = c2ssq[c] * (1.f / 32768.f) - mean * mean;
    float sc = g2[c] * rsqrtf(var + EPS);
    float sh = b2[c] - mean * sc;
    float v = (sc > 0.f) ? mm.x : mm.y;
    xfrag[i] = f2bf(fmaxf(0.f, fmaf(v, sc, sh)));
}

// fc1 MFMA: fused bn3 stats. Grid 128: blockIdx = bT*4 + ftg; wave -> 2 f-tiles.
__global__ __launch_bounds__(256) void k_fc1(const unsigned short* __restrict__ xfrag,
                                             const unsigned short* __restrict__ wfrag,
                                             float* __restrict__ out,
                                             float* __restrict__ sum,
                                             float* __restrict__ ssq) {
    int lane = threadIdx.x & 63;
    int wave = threadIdx.x >> 6;
    int fB = (blockIdx.x & 3) * 8 + wave * 2;
    int bT = blockIdx.x >> 2;
    v4f acc[2];
    acc[0] = (v4f){0,0,0,0}; acc[1] = (v4f){0,0,0,0};
    for (int ks = 0; ks < 64; ++ks) {
        v8s bfrag = *(const v8s*)(xfrag + ((size_t)(ks * 32 + bT) * 64 + lane) * 8);
        #pragma unroll
        for (int mt = 0; mt < 2; ++mt) {
            v8s afrag = *(const v8s*)(wfrag + ((size_t)(ks * 32 + fB + mt) * 64 + lane) * 8);
            acc[mt] = __builtin_amdgcn_mfma_f32_16x16x32_bf16(afrag, bfrag, acc[mt], 0, 0, 0);
        }
    }
    int bb = bT * 16 + (lane & 15);
    int quad = lane >> 4;
    #pragma unroll
    for (int mt = 0; mt < 2; ++mt) {
        int f0 = (fB + mt) * 16 + quad * 4;
        *(float4*)(&out[(size_t)bb * 512 + f0]) =
            make_float4(acc[mt][0], acc[mt][1], acc[mt][2], acc[mt][3]);
        #pragma unroll
        for (int r = 0; r < 4; ++r) {
            float s = acc[mt][r], s2 = s * s;
            #pragma unroll
            for (int m = 1; m < 16; m <<= 1) { s += __shfl_xor(s, m); s2 += __shfl_xor(s2, m); }
            if ((lane & 15) == 0) { atomicAdd(&sum[f0 + r], s); atomicAdd(&ssq[f0 + r], s2); }
        }
    }
}

// fc2 with inline bn3 finalize + relu: wave per batch row.
__global__ __launch_bounds__(256) void k_fc2(const float* __restrict__ x,
                                             const float* __restrict__ w,
                                             const float* __restrict__ bias,
                                             const float* __restrict__ fsum,
                                             const float* __restrict__ fssq,
                                             const float* __restrict__ g3,
                                             const float* __restrict__ b3,
                                             float* __restrict__ out) {
    int lane = threadIdx.x & 63;
    int b = blockIdx.x * 4 + (threadIdx.x >> 6);
    float xa[8], sm[8], sq[8], ga[8], ba[8];
    {
        const float4* p;
        p = (const float4*)(x + (size_t)b * 512 + lane * 8);
        *(float4*)xa = p[0]; *(float4*)(xa + 4) = p[1];
        p = (const float4*)(fsum + lane * 8);
        *(float4*)sm = p[0]; *(float4*)(sm + 4) = p[1];
        p = (const float4*)(fssq + lane * 8);
        *(float4*)sq = p[0]; *(float4*)(sq + 4) = p[1];
        p = (const float4*)(g3 + lane * 8);
        *(float4*)ga = p[0]; *(float4*)(ga + 4) = p[1];
        p = (const float4*)(b3 + lane * 8);
        *(float4*)ba = p[0]; *(float4*)(ba + 4) = p[1];
    }
    float h[8];
    #pragma unroll
    for (int e = 0; e < 8; ++e) {
        float mean = sm[e] * (1.f / 512.f);
        float var  = sq[e] * (1.f / 512.f) - mean * mean;
        float sc = ga[e] * rsqrtf(var + EPS);
        float sh = ba[e] - mean * sc;
        h[e] = fmaxf(0.f, fmaf(xa[e], sc, sh));
    }
    #pragma unroll
    for (int j = 0; j < 10; ++j) {
        const float4* wp = (const float4*)(w + j * 512 + lane * 8);
        float4 w0 = wp[0], w1 = wp[1];
        float p = h[0] * w0.x + h[1] * w0.y + h[2] * w0.z + h[3] * w0.w
                + h[4] * w1.x + h[5] * w1.y + h[6] * w1.z + h[7] * w1.w;
        #pragma unroll
        for (int o = 32; o; o >>= 1) p += __shfl_down(p, o);
        if (lane == 0) out[b * 10 + j] = p + bias[j];
    }
}

extern "C" void kernel_launch(void* const* d_in, const int* in_sizes, int n_in,
                              void* d_out, int out_size, void* d_ws, size_t ws_size,
                              hipStream_t stream) {
    const float* x       = (const float*)d_in[0];
    const float* conv1_w = (const float*)d_in[1];
    const float* bn1_g   = (const float*)d_in[3];
    const float* bn1_b   = (const float*)d_in[4];
    const float* conv2_w = (const float*)d_in[5];
    const float* bn2_g   = (const float*)d_in[7];
    const float* bn2_b   = (const float*)d_in[8];
    const float* fc1_w   = (const float*)d_in[9];
    const float* bn3_g   = (const float*)d_in[11];
    const float* bn3_b   = (const float*)d_in[12];
    const float* fc2_w   = (const float*)d_in[13];
    const float* fc2_b   = (const float*)d_in[14];
    // conv1_b / conv2_b / fc1_b are absorbed by train-mode BN

    float* wsf = (float*)d_ws;

    float* c2_sum = wsf + 272,  * c2_ssq = wsf + 400;
    float* f_sum  = wsf + 1808, * f_ssq  = wsf + 2320;
    float* Cg     = wsf + 2832;                      // 351 floats

    float* w1t = wsf + W1F;
    unsigned short* w2u = (unsigned short*)(wsf + W2F);
    float* wf2 = wsf + WF2F;
    unsigned short* wf1 = (unsigned short*)(wsf + WF1T);
    float* PMN = wsf + A_F;
    float* A   = wsf + A_F;                          // fc1out (PMN dead by then)
    unsigned short* pool1 = (unsigned short*)(wsf + B_F);
    unsigned short* xfrag = (unsigned short*)(wsf + B_F);

    // zero stats (absmax + sums + C)
    k_zero<<<16, 256, 0, stream>>>(wsf, 4096);

    // absmax (all 4 tensors)
    k_absmax4<<<210, 256, 0, stream>>>(conv1_w, 1600, conv2_w, 204800,
                                       fc1_w, 1048576, fc2_w, 5120, wsf);

    // quantize conv1 / conv2 (MFMA-frag bf16, scatter-write) / fc2
    k_quantE<<<102, 256, 0, stream>>>(conv1_w, conv2_w, fc2_w, wsf, w1t, w2u, wf2);

    // input autocorrelation -> C (weight-independent bn1 stats basis)
    k_xcorr<<<512, 384, 0, stream>>>(x, Cg);

    // conv1 + inline bn1 finalize + relu + pool -> pool1 NHWC bf16
    k_conv1B<<<512, 512, 0, stream>>>(x, w1t, Cg, bn1_g, bn1_b, pool1);

    // conv2 MFMA v5 (sp-half split, reg prefetch, fused stats + pool) -> PMN
    k_conv2<<<1024, 256, 0, stream>>>(pool1, w2u, PMN, c2_sum, c2_ssq);

    // fc1 weights -> bf16 A-frag (pool1 now dead)
    k_quantF1<<<4096, 256, 0, stream>>>(fc1_w, wsf, wf1);

    // bn2 (inline finalize) + relu on pooled pairs -> pool2 bf16 B-frag
    k_bnpool2<<<4096, 256, 0, stream>>>(PMN, c2_sum, c2_ssq, bn2_g, bn2_b, xfrag);

    // fc1 MFMA (fused bn3 stats) -> A fp32 [512,512]
    k_fc1<<<128, 256, 0, stream>>>(xfrag, wf1, A, f_sum, f_ssq);

    // fc2 (inline bn3 finalize + relu) -> d_out [512,10]
    k_fc2<<<128, 256, 0, stream>>>(A, wf2, fc2_b, f_sum, f_ssq, bn3_g, bn3_b,
                                   (float*)d_out);
}

// Round 10
// 307.831 us; speedup vs baseline: 1.7609x; 1.7609x over previous
//
#include <hip/hip_runtime.h>
#include <stdint.h>

#define EPS 1e-5f

typedef short v8s __attribute__((ext_vector_type(8)));
typedef float v4f __attribute__((ext_vector_type(4)));

// ---------------- ws float layout ----------------
//  [0,4)     absmax {c1,c2,f1,f2}
//  272/400  c2 sum/ssq (128 each)
//  1808 fc sum(512) 2320 fc ssq(512)
//  2832..3183: xcorr C matrix (351 floats, 26x26 upper-tri incl. means row)
//  W1F  = 4096    : conv1 weights float [k=25][c=64]
//  W2F  = 8192    : conv2 weights bf16 MFMA-frag order (204800 us)
//  WF2F = 212992  : fc2 weights float [j][512]
//  A_F  = 262144  : PMN fp32 [512][128][16][2]{max,min}; later fc1out fp32 [512,512]
//  B_F  = 19136512: pool1 bf16 NHWC [512][144][64]; later pool2 bf16 B-frag
//  WF1T = B_F + 1048576 : fc1 weights bf16 A-frag (written after conv2)
static const size_t W1F  = 4096;
static const size_t W2F  = 8192;
static const size_t WF2F = 212992;
static const size_t A_F  = 262144;
static const size_t B_F  = 19136512;
static const size_t WF1T = B_F + 1048576;

__device__ inline unsigned short f2bf(float f) {
    unsigned u = __float_as_uint(f);
    return (unsigned short)((u + 0x7FFF + ((u >> 16) & 1)) >> 16);
}

// async global->LDS, 16B per lane
__device__ __forceinline__ void stage16(const unsigned short* g, unsigned short* l) {
    __builtin_amdgcn_global_load_lds(
        (const __attribute__((address_space(1))) unsigned int*)g,
        (__attribute__((address_space(3))) unsigned int*)l, 16, 0, 0);
}

__global__ void k_zero(float* p, int n) {
    int i = blockIdx.x * blockDim.x + threadIdx.x;
    if (i < n) p[i] = 0.f;
}

// 4 absmax reductions in one launch
__global__ void k_absmax4(const float* __restrict__ w0, int n0,
                          const float* __restrict__ w1, int n1,
                          const float* __restrict__ w2, int n2,
                          const float* __restrict__ w3, int n3,
                          float* outv) {
    int blk = blockIdx.x;
    const float* w; int n; unsigned* out; int nb; int bi;
    if (blk < 1)        { w = w0; n = n0; out = (unsigned*)(outv + 0); nb = 1;   bi = blk;      }
    else if (blk < 17)  { w = w1; n = n1; out = (unsigned*)(outv + 1); nb = 16;  bi = blk - 1;  }
    else if (blk < 209) { w = w2; n = n2; out = (unsigned*)(outv + 2); nb = 192; bi = blk - 17; }
    else                { w = w3; n = n3; out = (unsigned*)(outv + 3); nb = 1;   bi = blk - 209; }
    float m = 0.f;
    for (int i = bi * 256 + threadIdx.x; i < n; i += nb * 256)
        m = fmaxf(m, fabsf(w[i]));
    #pragma unroll
    for (int o = 32; o; o >>= 1) m = fmaxf(m, __shfl_down(m, o));
    if ((threadIdx.x & 63) == 0) atomicMax(out, __float_as_uint(m));
}

// quantize: conv1 -> w1t float [k=25][c=64]; conv2 -> bf16 A-frag order (gather
// read, sequential write); fc2 float straight.
// conv2 frag: idx = ((p*2+ks)*8 + mt)*512 + lane*8 + j
//   = Q(conv2_w[c][ci][p]), c = mt*16 + (lane&15), ci = ks*32 + (lane>>4)*8 + j
__global__ void k_quantE(const float* __restrict__ c1w, const float* __restrict__ c2w,
                         const float* __restrict__ f2w, const float* __restrict__ am,
                         float* __restrict__ w1t, unsigned short* __restrict__ w2u,
                         float* __restrict__ wf2) {
    int blk = blockIdx.x;
    if (blk < 1) {
        float t = 0.05f * am[0];
        for (int i = threadIdx.x; i < 1600; i += 256) {
            float v = c1w[i];
            float q = (float)((v > t) - (v < -t));
            int c = i / 25, k = i - c * 25;
            w1t[k * 64 + c] = q;
        }
    } else if (blk < 101) {
        float t = 0.05f * am[1];
        int base = (blk - 1) * 2048;
        #pragma unroll
        for (int jj = 0; jj < 8; ++jj) {
            int i = base + jj * 256 + threadIdx.x;
            int j    = i & 7;
            int lane = (i >> 3) & 63;
            int mt   = (i >> 9) & 7;
            int ks   = (i >> 12) & 1;
            int p    = i >> 13;
            int c  = mt * 16 + (lane & 15);
            int ci = ks * 32 + (lane >> 4) * 8 + j;
            float v = c2w[c * 1600 + ci * 25 + p];
            w2u[i] = (v > t) ? (unsigned short)0x3F80
                             : ((v < -t) ? (unsigned short)0xBF80 : (unsigned short)0);
        }
    } else {
        float t = 0.05f * am[3];
        for (int i = threadIdx.x; i < 5120; i += 256) {
            float v = f2w[i];
            wf2[i] = (float)((v > t) - (v < -t));
        }
    }
}

// fc1 quantize -> bf16 A-frag (1048576 threads exactly)
__global__ void k_quantF1(const float* __restrict__ w, const float* __restrict__ am,
                          unsigned short* __restrict__ wf) {
    float t = 0.05f * am[2];
    int i = blockIdx.x * 256 + threadIdx.x;
    int j    = i & 7;
    int lane = (i >> 3) & 63;
    int ft   = (i >> 9) & 31;
    int ks   = i >> 14;
    int f = ft * 16 + (lane & 15);
    int k = ks * 32 + (lane >> 4) * 8 + j;
    float v = w[f * 2048 + k];
    wf[i] = (v > t) ? (unsigned short)0x3F80
                    : ((v < -t) ? (unsigned short)0xBF80 : (unsigned short)0);
}

// ---- xcorr v2: C[t(k,l)] = sum over (b,sp) of win_k*win_l; win[25]=1 (means row)
// 12 slots x <=30 pairs; grid 384 = 3 pair-groups x 128 image-chunks (4 imgs each).
static const int NPAIR = 351;
struct PTab { unsigned char k[NPAIR]; unsigned char l[NPAIR]; };
constexpr PTab mkPT() {
    PTab p{}; int t = 0;
    for (int a = 0; a < 26; ++a)
        for (int b = a; b < 26; ++b) { p.k[t] = (unsigned char)a; p.l[t] = (unsigned char)b; ++t; }
    return p;
}
constexpr PTab PT = mkPT();

template<int SLOT>
__device__ __forceinline__ void xcorr_win(const float* __restrict__ xs, int lane,
                                          float* __restrict__ acc) {
    constexpr int LO = SLOT * 30;
    constexpr int N  = (SLOT == 11) ? 21 : 30;
    for (int it = 0; it < 9; ++it) {
        int sp = it * 64 + lane;
        int oh = sp / 24, ow = sp - oh * 24;
        const float* xp = xs + oh * 28 + ow;
        float win[26];
        #pragma unroll
        for (int kh = 0; kh < 5; ++kh)
            #pragma unroll
            for (int kw = 0; kw < 5; ++kw)
                win[kh * 5 + kw] = xp[kh * 28 + kw];
        win[25] = 1.f;
        #pragma unroll
        for (int t = 0; t < N; ++t)
            acc[t] = fmaf(win[PT.k[LO + t]], win[PT.l[LO + t]], acc[t]);
    }
}

__global__ __launch_bounds__(256) void k_xcorr(const float* __restrict__ x,
                                               float* __restrict__ Cg) {
    __shared__ float xs[784];
    int pg   = blockIdx.x >> 7;            // 0..2
    int ic   = blockIdx.x & 127;           // image chunk of 4
    int wave = threadIdx.x >> 6, lane = threadIdx.x & 63;
    int slot = pg * 4 + wave;
    float acc[30];
    #pragma unroll
    for (int t = 0; t < 30; ++t) acc[t] = 0.f;
    for (int im = 0; im < 4; ++im) {
        const float4* xim = (const float4*)(x + (size_t)(ic * 4 + im) * 784);
        __syncthreads();
        for (int i = threadIdx.x; i < 196; i += 256) ((float4*)xs)[i] = xim[i];
        __syncthreads();
        switch (slot) {
            case 0:  xcorr_win<0 >(xs, lane, acc); break;
            case 1:  xcorr_win<1 >(xs, lane, acc); break;
            case 2:  xcorr_win<2 >(xs, lane, acc); break;
            case 3:  xcorr_win<3 >(xs, lane, acc); break;
            case 4:  xcorr_win<4 >(xs, lane, acc); break;
            case 5:  xcorr_win<5 >(xs, lane, acc); break;
            case 6:  xcorr_win<6 >(xs, lane, acc); break;
            case 7:  xcorr_win<7 >(xs, lane, acc); break;
            case 8:  xcorr_win<8 >(xs, lane, acc); break;
            case 9:  xcorr_win<9 >(xs, lane, acc); break;
            case 10: xcorr_win<10>(xs, lane, acc); break;
            default: xcorr_win<11>(xs, lane, acc); break;
        }
    }
    int LO = slot * 30;
    int N  = (slot == 11) ? 21 : 30;
    #pragma unroll
    for (int t = 0; t < 30; ++t) {
        if (t < N) {
            float r = acc[t];
            #pragma unroll
            for (int o = 32; o; o >>= 1) r += __shfl_down(r, o);
            if (lane == 0) atomicAdd(&Cg[LO + t], r);
        }
    }
}

// conv1B: inline bn1 finalize from C, then conv1+bn+relu+pool -> pool1 NHWC bf16
__global__ __launch_bounds__(512) void k_conv1B(const float* __restrict__ x,
                                                const float* __restrict__ w1t,
                                                const float* __restrict__ Cg,
                                                const float* __restrict__ g1,
                                                const float* __restrict__ b1,
                                                unsigned short* __restrict__ pool1) {
    __shared__ float xs[784];
    __shared__ float scsh[128];
    int b = blockIdx.x;
    const float4* xim = (const float4*)(x + (size_t)b * 784);
    for (int i = threadIdx.x; i < 196; i += 512) ((float4*)xs)[i] = xim[i];
    if (threadIdx.x < 64) {
        int c = threadIdx.x;
        float wq[25];
        #pragma unroll
        for (int k = 0; k < 25; ++k) wq[k] = w1t[k * 64 + c];
        float mean = 0.f, ey2 = 0.f;
        int t = 0;
        for (int k = 0; k < 26; ++k)
            for (int l = k; l < 26; ++l, ++t) {
                if (k == 25) continue;
                float Cv = Cg[t];
                if (l == 25) mean += wq[k] * Cv;
                else ey2 = fmaf(wq[k] * wq[l] * ((k == l) ? 1.f : 2.f), Cv, ey2);
            }
        const float invN = 1.f / 294912.f;
        mean *= invN; ey2 *= invN;
        float var = ey2 - mean * mean;
        float sc = g1[c] * rsqrtf(var + EPS);
        scsh[c] = sc; scsh[64 + c] = b1[c] - mean * sc;
    }
    int c  = threadIdx.x & 63;
    int wv = threadIdx.x >> 6;
    float w[25];
    #pragma unroll
    for (int k = 0; k < 25; ++k) w[k] = w1t[k * 64 + c];
    __syncthreads();
    float sc = scsh[c], sh = scsh[64 + c];
    unsigned short* ob = pool1 + (size_t)b * 9216;
    int ph = 0, pw = wv;
    for (int it = 0; it < 18; ++it) {
        const float* xp = xs + (ph * 2) * 28 + pw * 2;
        float win[36];
        #pragma unroll
        for (int i = 0; i < 6; ++i)
            #pragma unroll
            for (int j = 0; j < 3; ++j) {
                float2 t2 = *(const float2*)(xp + i * 28 + j * 2);
                win[i * 6 + j * 2] = t2.x; win[i * 6 + j * 2 + 1] = t2.y;
            }
        float v00 = 0.f, v01 = 0.f, v10 = 0.f, v11 = 0.f;
        #pragma unroll
        for (int i = 0; i < 5; ++i)
            #pragma unroll
            for (int j = 0; j < 5; ++j) {
                float wk = w[i * 5 + j];
                v00 = fmaf(win[i * 6 + j],           wk, v00);
                v01 = fmaf(win[i * 6 + j + 1],       wk, v01);
                v10 = fmaf(win[(i + 1) * 6 + j],     wk, v10);
                v11 = fmaf(win[(i + 1) * 6 + j + 1], wk, v11);
            }
        float r0 = fmaxf(0.f, fmaf(v00, sc, sh));
        float r1 = fmaxf(0.f, fmaf(v01, sc, sh));
        float r2 = fmaxf(0.f, fmaf(v10, sc, sh));
        float r3 = fmaxf(0.f, fmaf(v11, sc, sh));
        ob[(ph * 12 + pw) * 64 + c] = f2bf(fmaxf(fmaxf(r0, r1), fmaxf(r2, r3)));
        pw += 8; if (pw >= 12) { pw -= 12; ++ph; }
    }
}

// conv2 MFMA v3 (round-7, measured 50 us): LDS-dbuf weight tiles, 2x2 wave split,
// fused bn2 stats + fused 2x2 maxpool {max,min}. Block per image.
__global__ __launch_bounds__(256) void k_conv2(const unsigned short* __restrict__ pool1,
                                               const unsigned short* __restrict__ wfrag,
                                               float* __restrict__ pmn,
                                               float* __restrict__ sum,
                                               float* __restrict__ ssq) {
    __shared__ unsigned short xs[10368];       // act, ldci = 72
    __shared__ unsigned short wb[2][4096];     // 2 x 8KB weight tiles
    __shared__ float reds[2][128], redq[2][128];
    int b    = blockIdx.x;
    int tid  = threadIdx.x;
    int lane = tid & 63;
    int wave = tid >> 6;
    const unsigned short* src = pool1 + (size_t)b * 9216;
    for (int i = tid; i < 1152; i += 256) {
        int r = i >> 3, part = i & 7;
        *(float4*)(&xs[r * 72 + part * 8]) = *(const float4*)(src + r * 64 + part * 8);
    }
    {   // prefetch tile 0
        const unsigned short* g = wfrag + wave * 512 + lane * 8;
        stage16(g,        &wb[0][wave * 512 + lane * 8]);
        stage16(g + 2048, &wb[0][2048 + wave * 512 + lane * 8]);
    }
    __syncthreads();

    int mh = wave >> 1, nh = wave & 1;
    int n = lane & 15, quad = lane >> 4;
    int ow = n & 7;
    int ohb0 = nh * 4 + (n >> 3);              // oh of bf0; bf1 = +2
    int cib  = quad * 8;
    v4f acc[4][2];
    #pragma unroll
    for (int mm = 0; mm < 4; ++mm) { acc[mm][0] = (v4f){0,0,0,0}; acc[mm][1] = (v4f){0,0,0,0}; }
    int kh = 0, kw = 0;
    for (int step = 0; step < 50; ++step) {
        int cur = step & 1;
        if (step < 49) {
            const unsigned short* g = wfrag + (size_t)(step + 1) * 4096 + wave * 512 + lane * 8;
            stage16(g,        &wb[cur ^ 1][wave * 512 + lane * 8]);
            stage16(g + 2048, &wb[cur ^ 1][2048 + wave * 512 + lane * 8]);
        }
        int ks = step & 1;
        int col = (ow + kw) * 72 + ks * 32 + cib;
        v8s bf0 = *(const v8s*)(&xs[(ohb0 + kh) * 864 + col]);       // 12*72=864
        v8s bf1 = *(const v8s*)(&xs[(ohb0 + 2 + kh) * 864 + col]);
        #pragma unroll
        for (int mm = 0; mm < 4; ++mm) {
            v8s af = *(const v8s*)(&wb[cur][(mh * 4 + mm) * 512 + lane * 8]);
            acc[mm][0] = __builtin_amdgcn_mfma_f32_16x16x32_bf16(af, bf0, acc[mm][0], 0, 0, 0);
            acc[mm][1] = __builtin_amdgcn_mfma_f32_16x16x32_bf16(af, bf1, acc[mm][1], 0, 0, 0);
        }
        if (ks) { ++kw; if (kw == 5) { kw = 0; ++kh; } }
        __syncthreads();
    }
    // epilogue: pooled {max,min} + per-channel stats
    float* po = pmn + (size_t)b * 4096;        // [128][16][2]
    #pragma unroll
    for (int mm = 0; mm < 4; ++mm) {
        int c0 = (mh * 4 + mm) * 16 + quad * 4;
        #pragma unroll
        for (int r = 0; r < 4; ++r) {
            int c = c0 + r;
            float sA = 0.f, s2A = 0.f;
            #pragma unroll
            for (int bf = 0; bf < 2; ++bf) {
                float v = acc[mm][bf][r];
                float pm = fmaxf(v, __shfl_xor(v, 1));
                float pn = fminf(v, __shfl_xor(v, 1));
                pm = fmaxf(pm, __shfl_xor(pm, 8));
                pn = fminf(pn, __shfl_xor(pn, 8));
                if (((n & 1) == 0) && (n < 8)) {
                    int psp = (nh * 2 + bf) * 4 + (n >> 1);
                    *(float2*)(&po[(c * 16 + psp) * 2]) = make_float2(pm, pn);
                }
                float s = v, s2 = v * v;
                #pragma unroll
                for (int m = 1; m < 16; m <<= 1) { s += __shfl_xor(s, m); s2 += __shfl_xor(s2, m); }
                sA += s; s2A += s2;
            }
            if (n == 0) { reds[nh][c] = sA; redq[nh][c] = s2A; }
        }
    }
    __syncthreads();
    if (tid < 128) {
        atomicAdd(&sum[tid], reds[0][tid] + reds[1][tid]);
        atomicAdd(&ssq[tid], redq[0][tid] + redq[1][tid]);
    }
}

// bn2 finalize inline + relu on pooled pairs -> pool2 bf16 in fc1 B-frag order
__global__ void k_bnpool2(const float* __restrict__ pmn, const float* __restrict__ c2sum,
                          const float* __restrict__ c2ssq, const float* __restrict__ g2,
                          const float* __restrict__ b2, unsigned short* __restrict__ xfrag) {
    int i = blockIdx.x * 256 + threadIdx.x;    // 1048576
    int j    = i & 7;
    int lane = (i >> 3) & 63;
    int bt   = (i >> 9) & 31;
    int ks   = i >> 14;
    int b = bt * 16 + (lane & 15);
    int k = ks * 32 + (lane >> 4) * 8 + j;
    int c = k >> 4, psp = k & 15;
    float2 mm = *(const float2*)(&pmn[((size_t)b * 2048 + c * 16 + psp) * 2]);
    float mean = c2sum[c] * (1.f / 32768.f);
    float var  = c2ssq[c] * (1.f / 32768.f) - mean * mean;
    float sc = g2[c] * rsqrtf(var + EPS);
    float sh = b2[c] - mean * sc;
    float v = (sc > 0.f) ? mm.x : mm.y;
    xfrag[i] = f2bf(fmaxf(0.f, fmaf(v, sc, sh)));
}

// fc1 MFMA: fused bn3 stats. Grid 128: blockIdx = bT*4 + ftg; wave -> 2 f-tiles.
__global__ __launch_bounds__(256) void k_fc1(const unsigned short* __restrict__ xfrag,
                                             const unsigned short* __restrict__ wfrag,
                                             float* __restrict__ out,
                                             float* __restrict__ sum,
                                             float* __restrict__ ssq) {
    int lane = threadIdx.x & 63;
    int wave = threadIdx.x >> 6;
    int fB = (blockIdx.x & 3) * 8 + wave * 2;
    int bT = blockIdx.x >> 2;
    v4f acc[2];
    acc[0] = (v4f){0,0,0,0}; acc[1] = (v4f){0,0,0,0};
    for (int ks = 0; ks < 64; ++ks) {
        v8s bfrag = *(const v8s*)(xfrag + ((size_t)(ks * 32 + bT) * 64 + lane) * 8);
        #pragma unroll
        for (int mt = 0; mt < 2; ++mt) {
            v8s afrag = *(const v8s*)(wfrag + ((size_t)(ks * 32 + fB + mt) * 64 + lane) * 8);
            acc[mt] = __builtin_amdgcn_mfma_f32_16x16x32_bf16(afrag, bfrag, acc[mt], 0, 0, 0);
        }
    }
    int bb = bT * 16 + (lane & 15);
    int quad = lane >> 4;
    #pragma unroll
    for (int mt = 0; mt < 2; ++mt) {
        int f0 = (fB + mt) * 16 + quad * 4;
        *(float4*)(&out[(size_t)bb * 512 + f0]) =
            make_float4(acc[mt][0], acc[mt][1], acc[mt][2], acc[mt][3]);
        #pragma unroll
        for (int r = 0; r < 4; ++r) {
            float s = acc[mt][r], s2 = s * s;
            #pragma unroll
            for (int m = 1; m < 16; m <<= 1) { s += __shfl_xor(s, m); s2 += __shfl_xor(s2, m); }
            if ((lane & 15) == 0) { atomicAdd(&sum[f0 + r], s); atomicAdd(&ssq[f0 + r], s2); }
        }
    }
}

// fc2 with inline bn3 finalize + relu: wave per batch row.
__global__ __launch_bounds__(256) void k_fc2(const float* __restrict__ x,
                                             const float* __restrict__ w,
                                             const float* __restrict__ bias,
                                             const float* __restrict__ fsum,
                                             const float* __restrict__ fssq,
                                             const float* __restrict__ g3,
                                             const float* __restrict__ b3,
                                             float* __restrict__ out) {
    int lane = threadIdx.x & 63;
    int b = blockIdx.x * 4 + (threadIdx.x >> 6);
    float xa[8], sm[8], sq[8], ga[8], ba[8];
    {
        const float4* p;
        p = (const float4*)(x + (size_t)b * 512 + lane * 8);
        *(float4*)xa = p[0]; *(float4*)(xa + 4) = p[1];
        p = (const float4*)(fsum + lane * 8);
        *(float4*)sm = p[0]; *(float4*)(sm + 4) = p[1];
        p = (const float4*)(fssq + lane * 8);
        *(float4*)sq = p[0]; *(float4*)(sq + 4) = p[1];
        p = (const float4*)(g3 + lane * 8);
        *(float4*)ga = p[0]; *(float4*)(ga + 4) = p[1];
        p = (const float4*)(b3 + lane * 8);
        *(float4*)ba = p[0]; *(float4*)(ba + 4) = p[1];
    }
    float h[8];
    #pragma unroll
    for (int e = 0; e < 8; ++e) {
        float mean = sm[e] * (1.f / 512.f);
        float var  = sq[e] * (1.f / 512.f) - mean * mean;
        float sc = ga[e] * rsqrtf(var + EPS);
        float sh = ba[e] - mean * sc;
        h[e] = fmaxf(0.f, fmaf(xa[e], sc, sh));
    }
    #pragma unroll
    for (int j = 0; j < 10; ++j) {
        const float4* wp = (const float4*)(w + j * 512 + lane * 8);
        float4 w0 = wp[0], w1 = wp[1];
        float p = h[0] * w0.x + h[1] * w0.y + h[2] * w0.z + h[3] * w0.w
                + h[4] * w1.x + h[5] * w1.y + h[6] * w1.z + h[7] * w1.w;
        #pragma unroll
        for (int o = 32; o; o >>= 1) p += __shfl_down(p, o);
        if (lane == 0) out[b * 10 + j] = p + bias[j];
    }
}

extern "C" void kernel_launch(void* const* d_in, const int* in_sizes, int n_in,
                              void* d_out, int out_size, void* d_ws, size_t ws_size,
                              hipStream_t stream) {
    const float* x       = (const float*)d_in[0];
    const float* conv1_w = (const float*)d_in[1];
    const float* bn1_g   = (const float*)d_in[3];
    const float* bn1_b   = (const float*)d_in[4];
    const float* conv2_w = (const float*)d_in[5];
    const float* bn2_g   = (const float*)d_in[7];
    const float* bn2_b   = (const float*)d_in[8];
    const float* fc1_w   = (const float*)d_in[9];
    const float* bn3_g   = (const float*)d_in[11];
    const float* bn3_b   = (const float*)d_in[12];
    const float* fc2_w   = (const float*)d_in[13];
    const float* fc2_b   = (const float*)d_in[14];
    // conv1_b / conv2_b / fc1_b are absorbed by train-mode BN

    float* wsf = (float*)d_ws;

    float* c2_sum = wsf + 272,  * c2_ssq = wsf + 400;
    float* f_sum  = wsf + 1808, * f_ssq  = wsf + 2320;
    float* Cg     = wsf + 2832;                      // 351 floats

    float* w1t = wsf + W1F;
    unsigned short* w2u = (unsigned short*)(wsf + W2F);
    float* wf2 = wsf + WF2F;
    unsigned short* wf1 = (unsigned short*)(wsf + WF1T);
    float* PMN = wsf + A_F;
    float* A   = wsf + A_F;                          // fc1out (PMN dead by then)
    unsigned short* pool1 = (unsigned short*)(wsf + B_F);
    unsigned short* xfrag = (unsigned short*)(wsf + B_F);

    // zero stats (absmax + sums + C)
    k_zero<<<16, 256, 0, stream>>>(wsf, 4096);

    // absmax (all 4 tensors)
    k_absmax4<<<210, 256, 0, stream>>>(conv1_w, 1600, conv2_w, 204800,
                                       fc1_w, 1048576, fc2_w, 5120, wsf);

    // quantize conv1 / conv2 (MFMA-frag bf16) / fc2
    k_quantE<<<102, 256, 0, stream>>>(conv1_w, conv2_w, fc2_w, wsf, w1t, w2u, wf2);

    // input autocorrelation -> C (weight-independent bn1 stats basis)
    k_xcorr<<<384, 256, 0, stream>>>(x, Cg);

    // conv1 + inline bn1 finalize + relu + pool -> pool1 NHWC bf16
    k_conv1B<<<512, 512, 0, stream>>>(x, w1t, Cg, bn1_g, bn1_b, pool1);

    // conv2 MFMA v3 (known-good 50us) -> PMN + bn2 stats
    k_conv2<<<512, 256, 0, stream>>>(pool1, w2u, PMN, c2_sum, c2_ssq);

    // fc1 weights -> bf16 A-frag (pool1 now dead)
    k_quantF1<<<4096, 256, 0, stream>>>(fc1_w, wsf, wf1);

    // bn2 (inline finalize) + relu on pooled pairs -> pool2 bf16 B-frag
    k_bnpool2<<<4096, 256, 0, stream>>>(PMN, c2_sum, c2_ssq, bn2_g, bn2_b, xfrag);

    // fc1 MFMA (fused bn3 stats) -> A fp32 [512,512]
    k_fc1<<<128, 256, 0, stream>>>(xfrag, wf1, A, f_sum, f_ssq);

    // fc2 (inline bn3 finalize + relu) -> d_out [512,10]
    k_fc2<<<128, 256, 0, stream>>>(A, wf2, fc2_b, f_sum, f_ssq, bn3_g, bn3_b,
                                   (float*)d_out);
}

// Round 11
// 235.915 us; speedup vs baseline: 2.2976x; 1.3048x over previous
//
#include <hip/hip_runtime.h>
#include <stdint.h>

#define EPS 1e-5f

typedef short v8s __attribute__((ext_vector_type(8)));
typedef float v4f __attribute__((ext_vector_type(4)));

// ---------------- ws float layout ----------------
//  [0,4)     absmax {c1,c2,f1,f2}
//  16/80    c1 sum/ssq (64 each)
//  272/400  c2 sum/ssq (128 each)
//  1808 fc sum(512) 2320 fc ssq(512)
//  W1F  = 4096    : conv1 weights float [k=25][c=64]
//  W2F  = 8192    : conv2 weights bf16 MFMA-frag order (204800 us)
//  WF2F = 212992  : fc2 weights float [j][512]
//  A_F  = 262144  : PMN fp32 [512][128][16][2]{max,min}; later fc1out fp32 [512,512]
//  B_F  = 19136512: pool1 bf16 NHWC [512][144][64]; later pool2 bf16 B-frag
//  WF1T = B_F + 1048576 : fc1 weights bf16 A-frag (written after conv2)
static const size_t W1F  = 4096;
static const size_t W2F  = 8192;
static const size_t WF2F = 212992;
static const size_t A_F  = 262144;
static const size_t B_F  = 19136512;
static const size_t WF1T = B_F + 1048576;

__device__ inline unsigned short f2bf(float f) {
    unsigned u = __float_as_uint(f);
    return (unsigned short)((u + 0x7FFF + ((u >> 16) & 1)) >> 16);
}

// async global->LDS, 16B per lane
__device__ __forceinline__ void stage16(const unsigned short* g, unsigned short* l) {
    __builtin_amdgcn_global_load_lds(
        (const __attribute__((address_space(1))) unsigned int*)g,
        (__attribute__((address_space(3))) unsigned int*)l, 16, 0, 0);
}

__global__ void k_zero(float* p, int n) {
    int i = blockIdx.x * blockDim.x + threadIdx.x;
    if (i < n) p[i] = 0.f;
}

// 4 absmax reductions in one launch
__global__ void k_absmax4(const float* __restrict__ w0, int n0,
                          const float* __restrict__ w1, int n1,
                          const float* __restrict__ w2, int n2,
                          const float* __restrict__ w3, int n3,
                          float* outv) {
    int blk = blockIdx.x;
    const float* w; int n; unsigned* out; int nb; int bi;
    if (blk < 1)        { w = w0; n = n0; out = (unsigned*)(outv + 0); nb = 1;   bi = blk;      }
    else if (blk < 17)  { w = w1; n = n1; out = (unsigned*)(outv + 1); nb = 16;  bi = blk - 1;  }
    else if (blk < 209) { w = w2; n = n2; out = (unsigned*)(outv + 2); nb = 192; bi = blk - 17; }
    else                { w = w3; n = n3; out = (unsigned*)(outv + 3); nb = 1;   bi = blk - 209; }
    float m = 0.f;
    for (int i = bi * 256 + threadIdx.x; i < n; i += nb * 256)
        m = fmaxf(m, fabsf(w[i]));
    #pragma unroll
    for (int o = 32; o; o >>= 1) m = fmaxf(m, __shfl_down(m, o));
    if ((threadIdx.x & 63) == 0) atomicMax(out, __float_as_uint(m));
}

// quantize: conv1 -> w1t float [k=25][c=64]; conv2 -> bf16 A-frag order; fc2 float.
// conv2 frag: idx = ((p*2+ks)*8 + mt)*512 + lane*8 + j
//   = Q(conv2_w[c][ci][p]), c = mt*16 + (lane&15), ci = ks*32 + (lane>>4)*8 + j
__global__ void k_quantE(const float* __restrict__ c1w, const float* __restrict__ c2w,
                         const float* __restrict__ f2w, const float* __restrict__ am,
                         float* __restrict__ w1t, unsigned short* __restrict__ w2u,
                         float* __restrict__ wf2) {
    int blk = blockIdx.x;
    if (blk < 1) {
        float t = 0.05f * am[0];
        for (int i = threadIdx.x; i < 1600; i += 256) {
            float v = c1w[i];
            float q = (float)((v > t) - (v < -t));
            int c = i / 25, k = i - c * 25;
            w1t[k * 64 + c] = q;
        }
    } else if (blk < 101) {
        float t = 0.05f * am[1];
        int base = (blk - 1) * 2048;
        #pragma unroll
        for (int jj = 0; jj < 8; ++jj) {
            int i = base + jj * 256 + threadIdx.x;
            int j    = i & 7;
            int lane = (i >> 3) & 63;
            int mt   = (i >> 9) & 7;
            int ks   = (i >> 12) & 1;
            int p    = i >> 13;
            int c  = mt * 16 + (lane & 15);
            int ci = ks * 32 + (lane >> 4) * 8 + j;
            float v = c2w[c * 1600 + ci * 25 + p];
            w2u[i] = (v > t) ? (unsigned short)0x3F80
                             : ((v < -t) ? (unsigned short)0xBF80 : (unsigned short)0);
        }
    } else {
        float t = 0.05f * am[3];
        for (int i = threadIdx.x; i < 5120; i += 256) {
            float v = f2w[i];
            wf2[i] = (float)((v > t) - (v < -t));
        }
    }
}

// fc1 quantize -> bf16 A-frag (1048576 threads exactly)
__global__ void k_quantF1(const float* __restrict__ w, const float* __restrict__ am,
                          unsigned short* __restrict__ wf) {
    float t = 0.05f * am[2];
    int i = blockIdx.x * 256 + threadIdx.x;
    int j    = i & 7;
    int lane = (i >> 3) & 63;
    int ft   = (i >> 9) & 31;
    int ks   = i >> 14;
    int f = ft * 16 + (lane & 15);
    int k = ks * 32 + (lane >> 4) * 8 + j;
    float v = w[f * 2048 + k];
    wf[i] = (v > t) ? (unsigned short)0x3F80
                    : ((v < -t) ? (unsigned short)0xBF80 : (unsigned short)0);
}

// conv1 pass A: stats only. Block per image, 512 threads; lane = out channel.
__global__ __launch_bounds__(512) void k_conv1A(const float* __restrict__ x,
                                                const float* __restrict__ w1t,
                                                float* __restrict__ sum,
                                                float* __restrict__ ssq) {
    __shared__ float xs[784];
    __shared__ float red[2][8][64];
    int b = blockIdx.x;
    const float4* xim = (const float4*)(x + (size_t)b * 784);
    for (int i = threadIdx.x; i < 196; i += 512) ((float4*)xs)[i] = xim[i];
    int c  = threadIdx.x & 63;
    int wv = threadIdx.x >> 6;
    float w[25];
    #pragma unroll
    for (int k = 0; k < 25; ++k) w[k] = w1t[k * 64 + c];
    __syncthreads();
    float s = 0.f, s2 = 0.f;
    int oh = 0, ow = wv;
    for (int it = 0; it < 72; ++it) {
        const float* xp = xs + oh * 28 + ow;
        float acc = 0.f;
        #pragma unroll
        for (int kh = 0; kh < 5; ++kh)
            #pragma unroll
            for (int kw = 0; kw < 5; ++kw)
                acc = fmaf(xp[kh * 28 + kw], w[kh * 5 + kw], acc);
        s += acc; s2 += acc * acc;
        ow += 8; if (ow >= 24) { ow -= 24; ++oh; }
    }
    red[0][wv][c] = s; red[1][wv][c] = s2;
    __syncthreads();
    if (threadIdx.x < 64) {
        float S = 0.f, S2 = 0.f;
        #pragma unroll
        for (int i = 0; i < 8; ++i) { S += red[0][i][threadIdx.x]; S2 += red[1][i][threadIdx.x]; }
        atomicAdd(&sum[threadIdx.x], S);
        atomicAdd(&ssq[threadIdx.x], S2);
    }
}

// conv1B: inline bn1 finalize from sums (4 broadcast loads, no loop), then
// conv1+bn+relu+pool -> pool1 NHWC bf16 [b][144][64]
__global__ __launch_bounds__(512) void k_conv1B(const float* __restrict__ x,
                                                const float* __restrict__ w1t,
                                                const float* __restrict__ c1sum,
                                                const float* __restrict__ c1ssq,
                                                const float* __restrict__ g1,
                                                const float* __restrict__ b1,
                                                unsigned short* __restrict__ pool1) {
    __shared__ float xs[784];
    int b = blockIdx.x;
    const float4* xim = (const float4*)(x + (size_t)b * 784);
    for (int i = threadIdx.x; i < 196; i += 512) ((float4*)xs)[i] = xim[i];
    int c  = threadIdx.x & 63;
    int wv = threadIdx.x >> 6;
    float w[25];
    #pragma unroll
    for (int k = 0; k < 25; ++k) w[k] = w1t[k * 64 + c];
    const float invN = 1.f / 294912.f;
    float mean = c1sum[c] * invN;
    float var  = c1ssq[c] * invN - mean * mean;
    float sc = g1[c] * rsqrtf(var + EPS);
    float sh = b1[c] - mean * sc;
    __syncthreads();
    unsigned short* ob = pool1 + (size_t)b * 9216;
    int ph = 0, pw = wv;
    for (int it = 0; it < 18; ++it) {
        const float* xp = xs + (ph * 2) * 28 + pw * 2;
        float win[36];
        #pragma unroll
        for (int i = 0; i < 6; ++i)
            #pragma unroll
            for (int j = 0; j < 3; ++j) {
                float2 t2 = *(const float2*)(xp + i * 28 + j * 2);
                win[i * 6 + j * 2] = t2.x; win[i * 6 + j * 2 + 1] = t2.y;
            }
        float v00 = 0.f, v01 = 0.f, v10 = 0.f, v11 = 0.f;
        #pragma unroll
        for (int i = 0; i < 5; ++i)
            #pragma unroll
            for (int j = 0; j < 5; ++j) {
                float wk = w[i * 5 + j];
                v00 = fmaf(win[i * 6 + j],           wk, v00);
                v01 = fmaf(win[i * 6 + j + 1],       wk, v01);
                v10 = fmaf(win[(i + 1) * 6 + j],     wk, v10);
                v11 = fmaf(win[(i + 1) * 6 + j + 1], wk, v11);
            }
        float r0 = fmaxf(0.f, fmaf(v00, sc, sh));
        float r1 = fmaxf(0.f, fmaf(v01, sc, sh));
        float r2 = fmaxf(0.f, fmaf(v10, sc, sh));
        float r3 = fmaxf(0.f, fmaf(v11, sc, sh));
        ob[(ph * 12 + pw) * 64 + c] = f2bf(fmaxf(fmaxf(r0, r1), fmaxf(r2, r3)));
        pw += 8; if (pw >= 12) { pw -= 12; ++ph; }
    }
}

// conv2 MFMA v3.1: v3 structure, M split across 2 blocks -> grid 1024, 4 blocks/CU.
// LDS-dbuf weight tiles (4KB/step), 2x2 wave split within M=64, fused bn2 stats +
// fused 2x2 maxpool {max,min}.
__global__ __launch_bounds__(256) void k_conv2(const unsigned short* __restrict__ pool1,
                                               const unsigned short* __restrict__ wfrag,
                                               float* __restrict__ pmn,
                                               float* __restrict__ sum,
                                               float* __restrict__ ssq) {
    __shared__ unsigned short xs[10368];       // act, ldci = 72 (20736 B)
    __shared__ unsigned short wb[2][2048];     // 2 x 4KB weight tiles (4 mt frags)
    __shared__ float reds[2][64], redq[2][64];
    int b     = blockIdx.x >> 1;
    int mhalf = blockIdx.x & 1;
    int tid  = threadIdx.x;
    int lane = tid & 63;
    int wave = tid >> 6;
    const unsigned short* src = pool1 + (size_t)b * 9216;
    for (int i = tid; i < 1152; i += 256) {
        int r = i >> 3, part = i & 7;
        *(float4*)(&xs[r * 72 + part * 8]) = *(const float4*)(src + r * 64 + part * 8);
    }
    {   // prefetch step-0 weights: local tile = wave, global mt = mhalf*4 + wave
        const unsigned short* g = wfrag + (size_t)(mhalf * 4 + wave) * 512 + lane * 8;
        stage16(g, &wb[0][wave * 512 + lane * 8]);
    }
    __syncthreads();

    int mh = wave >> 1, nh = wave & 1;
    int n = lane & 15, quad = lane >> 4;
    int ow = n & 7;
    int ohb0 = nh * 4 + (n >> 3);              // oh of bf0; bf1 = +2
    int cib  = quad * 8;
    v4f acc[2][2];
    #pragma unroll
    for (int mm = 0; mm < 2; ++mm) { acc[mm][0] = (v4f){0,0,0,0}; acc[mm][1] = (v4f){0,0,0,0}; }
    int kh = 0, kw = 0;
    for (int step = 0; step < 50; ++step) {
        int cur = step & 1;
        if (step < 49) {
            const unsigned short* g = wfrag +
                (size_t)((step + 1) * 8 + mhalf * 4 + wave) * 512 + lane * 8;
            stage16(g, &wb[cur ^ 1][wave * 512 + lane * 8]);
        }
        int ks = step & 1;
        int col = (ow + kw) * 72 + ks * 32 + cib;
        v8s bf0 = *(const v8s*)(&xs[(ohb0 + kh) * 864 + col]);       // 12*72=864
        v8s bf1 = *(const v8s*)(&xs[(ohb0 + 2 + kh) * 864 + col]);
        #pragma unroll
        for (int mm = 0; mm < 2; ++mm) {
            v8s af = *(const v8s*)(&wb[cur][(mh * 2 + mm) * 512 + lane * 8]);
            acc[mm][0] = __builtin_amdgcn_mfma_f32_16x16x32_bf16(af, bf0, acc[mm][0], 0, 0, 0);
            acc[mm][1] = __builtin_amdgcn_mfma_f32_16x16x32_bf16(af, bf1, acc[mm][1], 0, 0, 0);
        }
        if (ks) { ++kw; if (kw == 5) { kw = 0; ++kh; } }
        __syncthreads();
    }
    // epilogue: pooled {max,min} + per-channel stats (64 ch within block)
    float* po = pmn + (size_t)b * 4096;        // [128][16][2]
    #pragma unroll
    for (int mm = 0; mm < 2; ++mm) {
        int cl0 = (mh * 2 + mm) * 16 + quad * 4;
        #pragma unroll
        for (int r = 0; r < 4; ++r) {
            int cl = cl0 + r;                  // 0..63 within block
            int c  = mhalf * 64 + cl;          // global channel
            float sA = 0.f, s2A = 0.f;
            #pragma unroll
            for (int bf = 0; bf < 2; ++bf) {
                float v = acc[mm][bf][r];
                float pm = fmaxf(v, __shfl_xor(v, 1));
                float pn = fminf(v, __shfl_xor(v, 1));
                pm = fmaxf(pm, __shfl_xor(pm, 8));
                pn = fminf(pn, __shfl_xor(pn, 8));
                if (((n & 1) == 0) && (n < 8)) {
                    int psp = (nh * 2 + bf) * 4 + (n >> 1);
                    *(float2*)(&po[(c * 16 + psp) * 2]) = make_float2(pm, pn);
                }
                float s = v, s2 = v * v;
                #pragma unroll
                for (int m = 1; m < 16; m <<= 1) { s += __shfl_xor(s, m); s2 += __shfl_xor(s2, m); }
                sA += s; s2A += s2;
            }
            if (n == 0) { reds[nh][cl] = sA; redq[nh][cl] = s2A; }
        }
    }
    __syncthreads();
    if (tid < 64) {
        atomicAdd(&sum[mhalf * 64 + tid], reds[0][tid] + reds[1][tid]);
        atomicAdd(&ssq[mhalf * 64 + tid], redq[0][tid] + redq[1][tid]);
    }
}

// bn2 finalize inline + relu on pooled pairs -> pool2 bf16 in fc1 B-frag order
__global__ void k_bnpool2(const float* __restrict__ pmn, const float* __restrict__ c2sum,
                          const float* __restrict__ c2ssq, const float* __restrict__ g2,
                          const float* __restrict__ b2, unsigned short* __restrict__ xfrag) {
    int i = blockIdx.x * 256 + threadIdx.x;    // 1048576
    int j    = i & 7;
    int lane = (i >> 3) & 63;
    int bt   = (i >> 9) & 31;
    int ks   = i >> 14;
    int b = bt * 16 + (lane & 15);
    int k = ks * 32 + (lane >> 4) * 8 + j;
    int c = k >> 4, psp = k & 15;
    float2 mm = *(const float2*)(&pmn[((size_t)b * 2048 + c * 16 + psp) * 2]);
    float mean = c2sum[c] * (1.f / 32768.f);
    float var  = c2ssq[c] * (1.f / 32768.f) - mean * mean;
    float sc = g2[c] * rsqrtf(var + EPS);
    float sh = b2[c] - mean * sc;
    float v = (sc > 0.f) ? mm.x : mm.y;
    xfrag[i] = f2bf(fmaxf(0.f, fmaf(v, sc, sh)));
}

// fc1 MFMA: fused bn3 stats. Grid 128: blockIdx = bT*4 + ftg; wave -> 2 f-tiles.
__global__ __launch_bounds__(256) void k_fc1(const unsigned short* __restrict__ xfrag,
                                             const unsigned short* __restrict__ wfrag,
                                             float* __restrict__ out,
                                             float* __restrict__ sum,
                                             float* __restrict__ ssq) {
    int lane = threadIdx.x & 63;
    int wave = threadIdx.x >> 6;
    int fB = (blockIdx.x & 3) * 8 + wave * 2;
    int bT = blockIdx.x >> 2;
    v4f acc[2];
    acc[0] = (v4f){0,0,0,0}; acc[1] = (v4f){0,0,0,0};
    for (int ks = 0; ks < 64; ++ks) {
        v8s bfrag = *(const v8s*)(xfrag + ((size_t)(ks * 32 + bT) * 64 + lane) * 8);
        #pragma unroll
        for (int mt = 0; mt < 2; ++mt) {
            v8s afrag = *(const v8s*)(wfrag + ((size_t)(ks * 32 + fB + mt) * 64 + lane) * 8);
            acc[mt] = __builtin_amdgcn_mfma_f32_16x16x32_bf16(afrag, bfrag, acc[mt], 0, 0, 0);
        }
    }
    int bb = bT * 16 + (lane & 15);
    int quad = lane >> 4;
    #pragma unroll
    for (int mt = 0; mt < 2; ++mt) {
        int f0 = (fB + mt) * 16 + quad * 4;
        *(float4*)(&out[(size_t)bb * 512 + f0]) =
            make_float4(acc[mt][0], acc[mt][1], acc[mt][2], acc[mt][3]);
        #pragma unroll
        for (int r = 0; r < 4; ++r) {
            float s = acc[mt][r], s2 = s * s;
            #pragma unroll
            for (int m = 1; m < 16; m <<= 1) { s += __shfl_xor(s, m); s2 += __shfl_xor(s2, m); }
            if ((lane & 15) == 0) { atomicAdd(&sum[f0 + r], s); atomicAdd(&ssq[f0 + r], s2); }
        }
    }
}

// fc2 with inline bn3 finalize + relu: wave per batch row.
__global__ __launch_bounds__(256) void k_fc2(const float* __restrict__ x,
                                             const float* __restrict__ w,
                                             const float* __restrict__ bias,
                                             const float* __restrict__ fsum,
                                             const float* __restrict__ fssq,
                                             const float* __restrict__ g3,
                                             const float* __restrict__ b3,
                                             float* __restrict__ out) {
    int lane = threadIdx.x & 63;
    int b = blockIdx.x * 4 + (threadIdx.x >> 6);
    float xa[8], sm[8], sq[8], ga[8], ba[8];
    {
        const float4* p;
        p = (const float4*)(x + (size_t)b * 512 + lane * 8);
        *(float4*)xa = p[0]; *(float4*)(xa + 4) = p[1];
        p = (const float4*)(fsum + lane * 8);
        *(float4*)sm = p[0]; *(float4*)(sm + 4) = p[1];
        p = (const float4*)(fssq + lane * 8);
        *(float4*)sq = p[0]; *(float4*)(sq + 4) = p[1];
        p = (const float4*)(g3 + lane * 8);
        *(float4*)ga = p[0]; *(float4*)(ga + 4) = p[1];
        p = (const float4*)(b3 + lane * 8);
        *(float4*)ba = p[0]; *(float4*)(ba + 4) = p[1];
    }
    float h[8];
    #pragma unroll
    for (int e = 0; e < 8; ++e) {
        float mean = sm[e] * (1.f / 512.f);
        float var  = sq[e] * (1.f / 512.f) - mean * mean;
        float sc = ga[e] * rsqrtf(var + EPS);
        float sh = ba[e] - mean * sc;
        h[e] = fmaxf(0.f, fmaf(xa[e], sc, sh));
    }
    #pragma unroll
    for (int j = 0; j < 10; ++j) {
        const float4* wp = (const float4*)(w + j * 512 + lane * 8);
        float4 w0 = wp[0], w1 = wp[1];
        float p = h[0] * w0.x + h[1] * w0.y + h[2] * w0.z + h[3] * w0.w
                + h[4] * w1.x + h[5] * w1.y + h[6] * w1.z + h[7] * w1.w;
        #pragma unroll
        for (int o = 32; o; o >>= 1) p += __shfl_down(p, o);
        if (lane == 0) out[b * 10 + j] = p + bias[j];
    }
}

extern "C" void kernel_launch(void* const* d_in, const int* in_sizes, int n_in,
                              void* d_out, int out_size, void* d_ws, size_t ws_size,
                              hipStream_t stream) {
    const float* x       = (const float*)d_in[0];
    const float* conv1_w = (const float*)d_in[1];
    const float* bn1_g   = (const float*)d_in[3];
    const float* bn1_b   = (const float*)d_in[4];
    const float* conv2_w = (const float*)d_in[5];
    const float* bn2_g   = (const float*)d_in[7];
    const float* bn2_b   = (const float*)d_in[8];
    const float* fc1_w   = (const float*)d_in[9];
    const float* bn3_g   = (const float*)d_in[11];
    const float* bn3_b   = (const float*)d_in[12];
    const float* fc2_w   = (const float*)d_in[13];
    const float* fc2_b   = (const float*)d_in[14];
    // conv1_b / conv2_b / fc1_b are absorbed by train-mode BN

    float* wsf = (float*)d_ws;

    float* c1_sum = wsf + 16,   * c1_ssq = wsf + 80;
    float* c2_sum = wsf + 272,  * c2_ssq = wsf + 400;
    float* f_sum  = wsf + 1808, * f_ssq  = wsf + 2320;

    float* w1t = wsf + W1F;
    unsigned short* w2u = (unsigned short*)(wsf + W2F);
    float* wf2 = wsf + WF2F;
    unsigned short* wf1 = (unsigned short*)(wsf + WF1T);
    float* PMN = wsf + A_F;
    float* A   = wsf + A_F;                          // fc1out (PMN dead by then)
    unsigned short* pool1 = (unsigned short*)(wsf + B_F);
    unsigned short* xfrag = (unsigned short*)(wsf + B_F);

    // zero stats (absmax + sums)
    k_zero<<<16, 256, 0, stream>>>(wsf, 4096);

    // absmax (all 4 tensors)
    k_absmax4<<<210, 256, 0, stream>>>(conv1_w, 1600, conv2_w, 204800,
                                       fc1_w, 1048576, fc2_w, 5120, wsf);

    // quantize conv1 / conv2 (MFMA-frag bf16) / fc2
    k_quantE<<<102, 256, 0, stream>>>(conv1_w, conv2_w, fc2_w, wsf, w1t, w2u, wf2);

    // conv1 pass A: stats only
    k_conv1A<<<512, 512, 0, stream>>>(x, w1t, c1_sum, c1_ssq);

    // conv1 pass B: inline bn1 finalize + conv + bn + relu + pool -> pool1 bf16
    k_conv1B<<<512, 512, 0, stream>>>(x, w1t, c1_sum, c1_ssq, bn1_g, bn1_b, pool1);

    // conv2 MFMA v3.1 (M-split, 4 blocks/CU) -> PMN + bn2 stats
    k_conv2<<<1024, 256, 0, stream>>>(pool1, w2u, PMN, c2_sum, c2_ssq);

    // fc1 weights -> bf16 A-frag (pool1 now dead)
    k_quantF1<<<4096, 256, 0, stream>>>(fc1_w, wsf, wf1);

    // bn2 (inline finalize) + relu on pooled pairs -> pool2 bf16 B-frag
    k_bnpool2<<<4096, 256, 0, stream>>>(PMN, c2_sum, c2_ssq, bn2_g, bn2_b, xfrag);

    // fc1 MFMA (fused bn3 stats) -> A fp32 [512,512]
    k_fc1<<<128, 256, 0, stream>>>(xfrag, wf1, A, f_sum, f_ssq);

    // fc2 (inline bn3 finalize + relu) -> d_out [512,10]
    k_fc2<<<128, 256, 0, stream>>>(A, wf2, fc2_b, f_sum, f_ssq, bn3_g, bn3_b,
                                   (float*)d_out);
}

// Round 12
// 224.111 us; speedup vs baseline: 2.4187x; 1.0527x over previous
//
#include <hip/hip_runtime.h>
#include <stdint.h>

#define EPS 1e-5f

typedef short v8s __attribute__((ext_vector_type(8)));
typedef float v4f __attribute__((ext_vector_type(4)));

// ---------------- ws float layout ----------------
//  [0,4)     absmax {c1,c2,f1,f2}
//  16/80    c1 sum/ssq (64 each)
//  272/400  c2 sum/ssq (128 each)
//  1808 fc sum(512) 2320 fc ssq(512)
//  W1F  = 4096    : conv1 weights float [k=25][c=64]
//  W2F  = 8192    : conv2 weights bf16 MFMA-frag order (204800 us)
//  WF2F = 212992  : fc2 weights float [j][512]
//  A_F  = 262144  : pmn1 packed uint [512][144][64] (4718592 slots);
//                   later PMN2 fp32 [512][128][16][2] (2097152 f);
//                   later fc1out fp32 [512,512]
//  B_F  = 19136512: pool1 bf16 NHWC [512][144][64]; later pool2 bf16 B-frag
//  WF1T = B_F + 1048576 : fc1 weights bf16 A-frag (written after conv2)
static const size_t W1F  = 4096;
static const size_t W2F  = 8192;
static const size_t WF2F = 212992;
static const size_t A_F  = 262144;
static const size_t B_F  = 19136512;
static const size_t WF1T = B_F + 1048576;

__device__ inline unsigned short f2bf(float f) {
    unsigned u = __float_as_uint(f);
    return (unsigned short)((u + 0x7FFF + ((u >> 16) & 1)) >> 16);
}

// async global->LDS, 16B per lane
__device__ __forceinline__ void stage16(const unsigned short* g, unsigned short* l) {
    __builtin_amdgcn_global_load_lds(
        (const __attribute__((address_space(1))) unsigned int*)g,
        (__attribute__((address_space(3))) unsigned int*)l, 16, 0, 0);
}

__global__ void k_zero(float* p, int n) {
    int i = blockIdx.x * blockDim.x + threadIdx.x;
    if (i < n) p[i] = 0.f;
}

// 4 absmax reductions in one launch
__global__ void k_absmax4(const float* __restrict__ w0, int n0,
                          const float* __restrict__ w1, int n1,
                          const float* __restrict__ w2, int n2,
                          const float* __restrict__ w3, int n3,
                          float* outv) {
    int blk = blockIdx.x;
    const float* w; int n; unsigned* out; int nb; int bi;
    if (blk < 1)        { w = w0; n = n0; out = (unsigned*)(outv + 0); nb = 1;   bi = blk;      }
    else if (blk < 17)  { w = w1; n = n1; out = (unsigned*)(outv + 1); nb = 16;  bi = blk - 1;  }
    else if (blk < 209) { w = w2; n = n2; out = (unsigned*)(outv + 2); nb = 192; bi = blk - 17; }
    else                { w = w3; n = n3; out = (unsigned*)(outv + 3); nb = 1;   bi = blk - 209; }
    float m = 0.f;
    for (int i = bi * 256 + threadIdx.x; i < n; i += nb * 256)
        m = fmaxf(m, fabsf(w[i]));
    #pragma unroll
    for (int o = 32; o; o >>= 1) m = fmaxf(m, __shfl_down(m, o));
    if ((threadIdx.x & 63) == 0) atomicMax(out, __float_as_uint(m));
}

// quantize: conv1 -> w1t float [k=25][c=64]; conv2 -> bf16 A-frag order; fc2 float.
// conv2 frag: idx = ((p*2+ks)*8 + mt)*512 + lane*8 + j
//   = Q(conv2_w[c][ci][p]), c = mt*16 + (lane&15), ci = ks*32 + (lane>>4)*8 + j
__global__ void k_quantE(const float* __restrict__ c1w, const float* __restrict__ c2w,
                         const float* __restrict__ f2w, const float* __restrict__ am,
                         float* __restrict__ w1t, unsigned short* __restrict__ w2u,
                         float* __restrict__ wf2) {
    int blk = blockIdx.x;
    if (blk < 1) {
        float t = 0.05f * am[0];
        for (int i = threadIdx.x; i < 1600; i += 256) {
            float v = c1w[i];
            float q = (float)((v > t) - (v < -t));
            int c = i / 25, k = i - c * 25;
            w1t[k * 64 + c] = q;
        }
    } else if (blk < 101) {
        float t = 0.05f * am[1];
        int base = (blk - 1) * 2048;
        #pragma unroll
        for (int jj = 0; jj < 8; ++jj) {
            int i = base + jj * 256 + threadIdx.x;
            int j    = i & 7;
            int lane = (i >> 3) & 63;
            int mt   = (i >> 9) & 7;
            int ks   = (i >> 12) & 1;
            int p    = i >> 13;
            int c  = mt * 16 + (lane & 15);
            int ci = ks * 32 + (lane >> 4) * 8 + j;
            float v = c2w[c * 1600 + ci * 25 + p];
            w2u[i] = (v > t) ? (unsigned short)0x3F80
                             : ((v < -t) ? (unsigned short)0xBF80 : (unsigned short)0);
        }
    } else {
        float t = 0.05f * am[3];
        for (int i = threadIdx.x; i < 5120; i += 256) {
            float v = f2w[i];
            wf2[i] = (float)((v > t) - (v < -t));
        }
    }
}

// fc1 quantize -> bf16 A-frag (1048576 threads exactly)
__global__ void k_quantF1(const float* __restrict__ w, const float* __restrict__ am,
                          unsigned short* __restrict__ wf) {
    float t = 0.05f * am[2];
    int i = blockIdx.x * 256 + threadIdx.x;
    int j    = i & 7;
    int lane = (i >> 3) & 63;
    int ft   = (i >> 9) & 31;
    int ks   = i >> 14;
    int f = ft * 16 + (lane & 15);
    int k = ks * 32 + (lane >> 4) * 8 + j;
    float v = w[f * 2048 + k];
    wf[i] = (v > t) ? (unsigned short)0x3F80
                    : ((v < -t) ? (unsigned short)0xBF80 : (unsigned short)0);
}

// conv1 single pass: conv + fused bn1 stats + packed {max,min} per pool window.
// Block per image, 512 threads; lane = out channel, wave = pool-window stripe.
__global__ __launch_bounds__(512) void k_conv1(const float* __restrict__ x,
                                               const float* __restrict__ w1t,
                                               unsigned* __restrict__ pmn1,
                                               float* __restrict__ sum,
                                               float* __restrict__ ssq) {
    __shared__ float xs[784];
    __shared__ float red[2][8][64];
    int b = blockIdx.x;
    const float4* xim = (const float4*)(x + (size_t)b * 784);
    for (int i = threadIdx.x; i < 196; i += 512) ((float4*)xs)[i] = xim[i];
    int c  = threadIdx.x & 63;
    int wv = threadIdx.x >> 6;
    float w[25];
    #pragma unroll
    for (int k = 0; k < 25; ++k) w[k] = w1t[k * 64 + c];
    __syncthreads();
    unsigned* ob = pmn1 + (size_t)b * 9216;
    float s = 0.f, s2 = 0.f;
    int ph = 0, pw = wv;
    for (int it = 0; it < 18; ++it) {
        const float* xp = xs + (ph * 2) * 28 + pw * 2;
        float win[36];
        #pragma unroll
        for (int i = 0; i < 6; ++i)
            #pragma unroll
            for (int j = 0; j < 3; ++j) {
                float2 t2 = *(const float2*)(xp + i * 28 + j * 2);
                win[i * 6 + j * 2] = t2.x; win[i * 6 + j * 2 + 1] = t2.y;
            }
        float v00 = 0.f, v01 = 0.f, v10 = 0.f, v11 = 0.f;
        #pragma unroll
        for (int i = 0; i < 5; ++i)
            #pragma unroll
            for (int j = 0; j < 5; ++j) {
                float wk = w[i * 5 + j];
                v00 = fmaf(win[i * 6 + j],           wk, v00);
                v01 = fmaf(win[i * 6 + j + 1],       wk, v01);
                v10 = fmaf(win[(i + 1) * 6 + j],     wk, v10);
                v11 = fmaf(win[(i + 1) * 6 + j + 1], wk, v11);
            }
        s  += v00 + v01 + v10 + v11;
        s2 += v00 * v00 + v01 * v01 + v10 * v10 + v11 * v11;
        float mx = fmaxf(fmaxf(v00, v01), fmaxf(v10, v11));
        float mn = fminf(fminf(v00, v01), fminf(v10, v11));
        ob[(ph * 12 + pw) * 64 + c] = ((unsigned)f2bf(mx) << 16) | (unsigned)f2bf(mn);
        pw += 8; if (pw >= 12) { pw -= 12; ++ph; }
    }
    red[0][wv][c] = s; red[1][wv][c] = s2;
    __syncthreads();
    if (threadIdx.x < 64) {
        float S = 0.f, S2 = 0.f;
        #pragma unroll
        for (int i = 0; i < 8; ++i) { S += red[0][i][threadIdx.x]; S2 += red[1][i][threadIdx.x]; }
        atomicAdd(&sum[threadIdx.x], S);
        atomicAdd(&ssq[threadIdx.x], S2);
    }
}

// bn1 (inline finalize) + relu + pool-select on packed pairs -> pool1 NHWC bf16
__global__ void k_bnpool1(const unsigned* __restrict__ pmn1,
                          const float* __restrict__ c1sum, const float* __restrict__ c1ssq,
                          const float* __restrict__ g1, const float* __restrict__ b1,
                          unsigned short* __restrict__ pool1) {
    int i = blockIdx.x * 256 + threadIdx.x;    // 4718592
    int c = i & 63;
    const float invN = 1.f / 294912.f;
    float mean = c1sum[c] * invN;
    float var  = c1ssq[c] * invN - mean * mean;
    float sc = g1[c] * rsqrtf(var + EPS);
    float sh = b1[c] - mean * sc;
    unsigned u = pmn1[i];
    float mx = __uint_as_float(u & 0xffff0000u);
    float mn = __uint_as_float(u << 16);
    float v = (sc > 0.f) ? mx : mn;
    pool1[i] = f2bf(fmaxf(0.f, fmaf(v, sc, sh)));
}

// conv2 MFMA v3.2: M-split grid 1024 (4 blocks/CU), 2 K-steps per barrier
// (8 MFMAs/wave between drains), ldci pad 76 (6-bank ow stride).
__global__ __launch_bounds__(256) void k_conv2(const unsigned short* __restrict__ pool1,
                                               const unsigned short* __restrict__ wfrag,
                                               float* __restrict__ pmn,
                                               float* __restrict__ sum,
                                               float* __restrict__ ssq) {
    __shared__ unsigned short xs[144 * 76];    // [oh*12+ow][ci pad76] = 21888 B
    __shared__ unsigned short wb[2][4096];     // 2 x 8KB (2 K-steps each)
    __shared__ float reds[2][64], redq[2][64];
    int b     = blockIdx.x >> 1;
    int mhalf = blockIdx.x & 1;
    int tid  = threadIdx.x;
    int lane = tid & 63;
    int wave = tid >> 6;
    const unsigned short* src = pool1 + (size_t)b * 9216;
    for (int i = tid; i < 1152; i += 256) {
        int r = i >> 3, part = i & 7;
        *(float4*)(&xs[r * 76 + part * 8]) = *(const float4*)(src + r * 64 + part * 8);
    }
    // prefetch steps 0,1 into wb[0]
    #pragma unroll
    for (int h = 0; h < 2; ++h) {
        const unsigned short* g = wfrag + (size_t)(h * 8 + mhalf * 4 + wave) * 512 + lane * 8;
        stage16(g, &wb[0][h * 2048 + wave * 512 + lane * 8]);
    }
    __syncthreads();

    int mh = wave >> 1, nh = wave & 1;
    int n = lane & 15, quad = lane >> 4;
    int ow = n & 7;
    int ohb0 = nh * 4 + (n >> 3);              // oh of bf0; bf1 = +2
    int cib  = quad * 8;
    v4f acc[2][2];
    #pragma unroll
    for (int mm = 0; mm < 2; ++mm) { acc[mm][0] = (v4f){0,0,0,0}; acc[mm][1] = (v4f){0,0,0,0}; }
    for (int ss = 0; ss < 25; ++ss) {          // ss = p (kernel position)
        int cur = ss & 1;
        if (ss < 24) {
            #pragma unroll
            for (int h = 0; h < 2; ++h) {
                int st = 2 * ss + 2 + h;
                const unsigned short* g = wfrag +
                    (size_t)(st * 8 + mhalf * 4 + wave) * 512 + lane * 8;
                stage16(g, &wb[cur ^ 1][h * 2048 + wave * 512 + lane * 8]);
            }
        }
        int kh = ss / 5, kw = ss - (ss / 5) * 5;
        #pragma unroll
        for (int ks = 0; ks < 2; ++ks) {
            int col = (ow + kw) * 76 + ks * 32 + cib;
            v8s bf0 = *(const v8s*)(&xs[(ohb0 + kh) * 912 + col]);   // 12*76=912
            v8s bf1 = *(const v8s*)(&xs[(ohb0 + 2 + kh) * 912 + col]);
            #pragma unroll
            for (int mm = 0; mm < 2; ++mm) {
                v8s af = *(const v8s*)(&wb[cur][ks * 2048 + (mh * 2 + mm) * 512 + lane * 8]);
                acc[mm][0] = __builtin_amdgcn_mfma_f32_16x16x32_bf16(af, bf0, acc[mm][0], 0, 0, 0);
                acc[mm][1] = __builtin_amdgcn_mfma_f32_16x16x32_bf16(af, bf1, acc[mm][1], 0, 0, 0);
            }
        }
        __syncthreads();
    }
    // epilogue: pooled {max,min} + per-channel stats (64 ch within block)
    float* po = pmn + (size_t)b * 4096;        // [128][16][2]
    #pragma unroll
    for (int mm = 0; mm < 2; ++mm) {
        int cl0 = (mh * 2 + mm) * 16 + quad * 4;
        #pragma unroll
        for (int r = 0; r < 4; ++r) {
            int cl = cl0 + r;
            int c  = mhalf * 64 + cl;
            float sA = 0.f, s2A = 0.f;
            #pragma unroll
            for (int bf = 0; bf < 2; ++bf) {
                float v = acc[mm][bf][r];
                float pm = fmaxf(v, __shfl_xor(v, 1));
                float pn = fminf(v, __shfl_xor(v, 1));
                pm = fmaxf(pm, __shfl_xor(pm, 8));
                pn = fminf(pn, __shfl_xor(pn, 8));
                if (((n & 1) == 0) && (n < 8)) {
                    int psp = (nh * 2 + bf) * 4 + (n >> 1);
                    *(float2*)(&po[(c * 16 + psp) * 2]) = make_float2(pm, pn);
                }
                float s = v, s2 = v * v;
                #pragma unroll
                for (int m = 1; m < 16; m <<= 1) { s += __shfl_xor(s, m); s2 += __shfl_xor(s2, m); }
                sA += s; s2A += s2;
            }
            if (n == 0) { reds[nh][cl] = sA; redq[nh][cl] = s2A; }
        }
    }
    __syncthreads();
    if (tid < 64) {
        atomicAdd(&sum[mhalf * 64 + tid], reds[0][tid] + reds[1][tid]);
        atomicAdd(&ssq[mhalf * 64 + tid], redq[0][tid] + redq[1][tid]);
    }
}

// bn2 finalize inline + relu on pooled pairs -> pool2 bf16 in fc1 B-frag order
__global__ void k_bnpool2(const float* __restrict__ pmn, const float* __restrict__ c2sum,
                          const float* __restrict__ c2ssq, const float* __restrict__ g2,
                          const float* __restrict__ b2, unsigned short* __restrict__ xfrag) {
    int i = blockIdx.x * 256 + threadIdx.x;    // 1048576
    int j    = i & 7;
    int lane = (i >> 3) & 63;
    int bt   = (i >> 9) & 31;
    int ks   = i >> 14;
    int b = bt * 16 + (lane & 15);
    int k = ks * 32 + (lane >> 4) * 8 + j;
    int c = k >> 4, psp = k & 15;
    float2 mm = *(const float2*)(&pmn[((size_t)b * 2048 + c * 16 + psp) * 2]);
    float mean = c2sum[c] * (1.f / 32768.f);
    float var  = c2ssq[c] * (1.f / 32768.f) - mean * mean;
    float sc = g2[c] * rsqrtf(var + EPS);
    float sh = b2[c] - mean * sc;
    float v = (sc > 0.f) ? mm.x : mm.y;
    xfrag[i] = f2bf(fmaxf(0.f, fmaf(v, sc, sh)));
}

// fc1 MFMA: fused bn3 stats. Grid 128: blockIdx = bT*4 + ftg; wave -> 2 f-tiles.
__global__ __launch_bounds__(256) void k_fc1(const unsigned short* __restrict__ xfrag,
                                             const unsigned short* __restrict__ wfrag,
                                             float* __restrict__ out,
                                             float* __restrict__ sum,
                                             float* __restrict__ ssq) {
    int lane = threadIdx.x & 63;
    int wave = threadIdx.x >> 6;
    int fB = (blockIdx.x & 3) * 8 + wave * 2;
    int bT = blockIdx.x >> 2;
    v4f acc[2];
    acc[0] = (v4f){0,0,0,0}; acc[1] = (v4f){0,0,0,0};
    for (int ks = 0; ks < 64; ++ks) {
        v8s bfrag = *(const v8s*)(xfrag + ((size_t)(ks * 32 + bT) * 64 + lane) * 8);
        #pragma unroll
        for (int mt = 0; mt < 2; ++mt) {
            v8s afrag = *(const v8s*)(wfrag + ((size_t)(ks * 32 + fB + mt) * 64 + lane) * 8);
            acc[mt] = __builtin_amdgcn_mfma_f32_16x16x32_bf16(afrag, bfrag, acc[mt], 0, 0, 0);
        }
    }
    int bb = bT * 16 + (lane & 15);
    int quad = lane >> 4;
    #pragma unroll
    for (int mt = 0; mt < 2; ++mt) {
        int f0 = (fB + mt) * 16 + quad * 4;
        *(float4*)(&out[(size_t)bb * 512 + f0]) =
            make_float4(acc[mt][0], acc[mt][1], acc[mt][2], acc[mt][3]);
        #pragma unroll
        for (int r = 0; r < 4; ++r) {
            float s = acc[mt][r], s2 = s * s;
            #pragma unroll
            for (int m = 1; m < 16; m <<= 1) { s += __shfl_xor(s, m); s2 += __shfl_xor(s2, m); }
            if ((lane & 15) == 0) { atomicAdd(&sum[f0 + r], s); atomicAdd(&ssq[f0 + r], s2); }
        }
    }
}

// fc2 with inline bn3 finalize + relu: wave per batch row.
__global__ __launch_bounds__(256) void k_fc2(const float* __restrict__ x,
                                             const float* __restrict__ w,
                                             const float* __restrict__ bias,
                                             const float* __restrict__ fsum,
                                             const float* __restrict__ fssq,
                                             const float* __restrict__ g3,
                                             const float* __restrict__ b3,
                                             float* __restrict__ out) {
    int lane = threadIdx.x & 63;
    int b = blockIdx.x * 4 + (threadIdx.x >> 6);
    float xa[8], sm[8], sq[8], ga[8], ba[8];
    {
        const float4* p;
        p = (const float4*)(x + (size_t)b * 512 + lane * 8);
        *(float4*)xa = p[0]; *(float4*)(xa + 4) = p[1];
        p = (const float4*)(fsum + lane * 8);
        *(float4*)sm = p[0]; *(float4*)(sm + 4) = p[1];
        p = (const float4*)(fssq + lane * 8);
        *(float4*)sq = p[0]; *(float4*)(sq + 4) = p[1];
        p = (const float4*)(g3 + lane * 8);
        *(float4*)ga = p[0]; *(float4*)(ga + 4) = p[1];
        p = (const float4*)(b3 + lane * 8);
        *(float4*)ba = p[0]; *(float4*)(ba + 4) = p[1];
    }
    float h[8];
    #pragma unroll
    for (int e = 0; e < 8; ++e) {
        float mean = sm[e] * (1.f / 512.f);
        float var  = sq[e] * (1.f / 512.f) - mean * mean;
        float sc = ga[e] * rsqrtf(var + EPS);
        float sh = ba[e] - mean * sc;
        h[e] = fmaxf(0.f, fmaf(xa[e], sc, sh));
    }
    #pragma unroll
    for (int j = 0; j < 10; ++j) {
        const float4* wp = (const float4*)(w + j * 512 + lane * 8);
        float4 w0 = wp[0], w1 = wp[1];
        float p = h[0] * w0.x + h[1] * w0.y + h[2] * w0.z + h[3] * w0.w
                + h[4] * w1.x + h[5] * w1.y + h[6] * w1.z + h[7] * w1.w;
        #pragma unroll
        for (int o = 32; o; o >>= 1) p += __shfl_down(p, o);
        if (lane == 0) out[b * 10 + j] = p + bias[j];
    }
}

extern "C" void kernel_launch(void* const* d_in, const int* in_sizes, int n_in,
                              void* d_out, int out_size, void* d_ws, size_t ws_size,
                              hipStream_t stream) {
    const float* x       = (const float*)d_in[0];
    const float* conv1_w = (const float*)d_in[1];
    const float* bn1_g   = (const float*)d_in[3];
    const float* bn1_b   = (const float*)d_in[4];
    const float* conv2_w = (const float*)d_in[5];
    const float* bn2_g   = (const float*)d_in[7];
    const float* bn2_b   = (const float*)d_in[8];
    const float* fc1_w   = (const float*)d_in[9];
    const float* bn3_g   = (const float*)d_in[11];
    const float* bn3_b   = (const float*)d_in[12];
    const float* fc2_w   = (const float*)d_in[13];
    const float* fc2_b   = (const float*)d_in[14];
    // conv1_b / conv2_b / fc1_b are absorbed by train-mode BN

    float* wsf = (float*)d_ws;

    float* c1_sum = wsf + 16,   * c1_ssq = wsf + 80;
    float* c2_sum = wsf + 272,  * c2_ssq = wsf + 400;
    float* f_sum  = wsf + 1808, * f_ssq  = wsf + 2320;

    float* w1t = wsf + W1F;
    unsigned short* w2u = (unsigned short*)(wsf + W2F);
    float* wf2 = wsf + WF2F;
    unsigned short* wf1 = (unsigned short*)(wsf + WF1T);
    unsigned* PMN1 = (unsigned*)(wsf + A_F);         // [512][144][64] packed
    float* PMN2 = wsf + A_F;                         // [512][128][16][2] (pmn1 dead)
    float* A    = wsf + A_F;                         // fc1out (PMN2 dead by then)
    unsigned short* pool1 = (unsigned short*)(wsf + B_F);
    unsigned short* xfrag = (unsigned short*)(wsf + B_F);

    // zero stats (absmax + sums)
    k_zero<<<16, 256, 0, stream>>>(wsf, 4096);

    // absmax (all 4 tensors)
    k_absmax4<<<210, 256, 0, stream>>>(conv1_w, 1600, conv2_w, 204800,
                                       fc1_w, 1048576, fc2_w, 5120, wsf);

    // quantize conv1 / conv2 (MFMA-frag bf16) / fc2
    k_quantE<<<102, 256, 0, stream>>>(conv1_w, conv2_w, fc2_w, wsf, w1t, w2u, wf2);

    // conv1 single pass: stats + packed {max,min} -> PMN1
    k_conv1<<<512, 512, 0, stream>>>(x, w1t, PMN1, c1_sum, c1_ssq);

    // bn1 finalize + relu + pool-select -> pool1 NHWC bf16
    k_bnpool1<<<18432, 256, 0, stream>>>(PMN1, c1_sum, c1_ssq, bn1_g, bn1_b, pool1);

    // conv2 MFMA v3.2 (2 K-steps/barrier, pad 76) -> PMN2 + bn2 stats
    k_conv2<<<1024, 256, 0, stream>>>(pool1, w2u, PMN2, c2_sum, c2_ssq);

    // fc1 weights -> bf16 A-frag (pool1 now dead)
    k_quantF1<<<4096, 256, 0, stream>>>(fc1_w, wsf, wf1);

    // bn2 (inline finalize) + relu on pooled pairs -> pool2 bf16 B-frag
    k_bnpool2<<<4096, 256, 0, stream>>>(PMN2, c2_sum, c2_ssq, bn2_g, bn2_b, xfrag);

    // fc1 MFMA (fused bn3 stats) -> A fp32 [512,512]
    k_fc1<<<128, 256, 0, stream>>>(xfrag, wf1, A, f_sum, f_ssq);

    // fc2 (inline bn3 finalize + relu) -> d_out [512,10]
    k_fc2<<<128, 256, 0, stream>>>(A, wf2, fc2_b, f_sum, f_ssq, bn3_g, bn3_b,
                                   (float*)d_out);
}

// Round 13
// 214.146 us; speedup vs baseline: 2.5312x; 1.0465x over previous
//
#include <hip/hip_runtime.h>
#include <stdint.h>

#define EPS 1e-5f

typedef short v8s __attribute__((ext_vector_type(8)));
typedef float v4f __attribute__((ext_vector_type(4)));

// ---------------- ws float layout ----------------
//  [0,4)     absmax {c1,c2,f1,f2}
//  16/80    c1 sum/ssq (64 each)
//  272/400  c2 sum/ssq (128 each)
//  1808 fc sum(512) 2320 fc ssq(512)
//  W1F  = 4096    : conv1 weights float [k=25][c=64]
//  W2F  = 8192    : conv2 weights bf16 MFMA-frag order (204800 us)
//  WF2F = 212992  : fc2 weights float [j][512]
//  A_F  = 262144  : pmn1 packed uint [512][144][64]; later PMN2 fp32
//                   [512][128][16][2]; later fc1out fp32 [512,512]
//  B_F  = 19136512: pool1 bf16 NHWC [512][144][64]; later pool2 bf16 B-frag
//  WF1T = B_F + 1048576 : fc1 weights bf16 A-frag (written after conv2)
static const size_t W1F  = 4096;
static const size_t W2F  = 8192;
static const size_t WF2F = 212992;
static const size_t A_F  = 262144;
static const size_t B_F  = 19136512;
static const size_t WF1T = B_F + 1048576;

__device__ inline unsigned short f2bf(float f) {
    unsigned u = __float_as_uint(f);
    return (unsigned short)((u + 0x7FFF + ((u >> 16) & 1)) >> 16);
}

// async global->LDS, 16B per lane
__device__ __forceinline__ void stage16(const unsigned short* g, unsigned short* l) {
    __builtin_amdgcn_global_load_lds(
        (const __attribute__((address_space(1))) unsigned int*)g,
        (__attribute__((address_space(3))) unsigned int*)l, 16, 0, 0);
}

__global__ void k_zero(float* p, int n) {
    int i = blockIdx.x * blockDim.x + threadIdx.x;
    if (i < n) p[i] = 0.f;
}

// 4 absmax reductions in one launch
__global__ void k_absmax4(const float* __restrict__ w0, int n0,
                          const float* __restrict__ w1, int n1,
                          const float* __restrict__ w2, int n2,
                          const float* __restrict__ w3, int n3,
                          float* outv) {
    int blk = blockIdx.x;
    const float* w; int n; unsigned* out; int nb; int bi;
    if (blk < 1)        { w = w0; n = n0; out = (unsigned*)(outv + 0); nb = 1;   bi = blk;      }
    else if (blk < 17)  { w = w1; n = n1; out = (unsigned*)(outv + 1); nb = 16;  bi = blk - 1;  }
    else if (blk < 209) { w = w2; n = n2; out = (unsigned*)(outv + 2); nb = 192; bi = blk - 17; }
    else                { w = w3; n = n3; out = (unsigned*)(outv + 3); nb = 1;   bi = blk - 209; }
    float m = 0.f;
    for (int i = bi * 256 + threadIdx.x; i < n; i += nb * 256)
        m = fmaxf(m, fabsf(w[i]));
    #pragma unroll
    for (int o = 32; o; o >>= 1) m = fmaxf(m, __shfl_down(m, o));
    if ((threadIdx.x & 63) == 0) atomicMax(out, __float_as_uint(m));
}

// quantize: conv1 -> w1t float [k=25][c=64]; conv2 -> bf16 A-frag order; fc2 float.
// conv2 frag: idx = ((p*2+ks)*8 + mt)*512 + lane*8 + j
//   = Q(conv2_w[c][ci][p]), c = mt*16 + (lane&15), ci = ks*32 + (lane>>4)*8 + j
__global__ void k_quantE(const float* __restrict__ c1w, const float* __restrict__ c2w,
                         const float* __restrict__ f2w, const float* __restrict__ am,
                         float* __restrict__ w1t, unsigned short* __restrict__ w2u,
                         float* __restrict__ wf2) {
    int blk = blockIdx.x;
    if (blk < 1) {
        float t = 0.05f * am[0];
        for (int i = threadIdx.x; i < 1600; i += 256) {
            float v = c1w[i];
            float q = (float)((v > t) - (v < -t));
            int c = i / 25, k = i - c * 25;
            w1t[k * 64 + c] = q;
        }
    } else if (blk < 101) {
        float t = 0.05f * am[1];
        int base = (blk - 1) * 2048;
        #pragma unroll
        for (int jj = 0; jj < 8; ++jj) {
            int i = base + jj * 256 + threadIdx.x;
            int j    = i & 7;
            int lane = (i >> 3) & 63;
            int mt   = (i >> 9) & 7;
            int ks   = (i >> 12) & 1;
            int p    = i >> 13;
            int c  = mt * 16 + (lane & 15);
            int ci = ks * 32 + (lane >> 4) * 8 + j;
            float v = c2w[c * 1600 + ci * 25 + p];
            w2u[i] = (v > t) ? (unsigned short)0x3F80
                             : ((v < -t) ? (unsigned short)0xBF80 : (unsigned short)0);
        }
    } else {
        float t = 0.05f * am[3];
        for (int i = threadIdx.x; i < 5120; i += 256) {
            float v = f2w[i];
            wf2[i] = (float)((v > t) - (v < -t));
        }
    }
}

// fc1 quantize, f-major (coalesced reads, 16B chunk scatter writes) -> bf16 A-frag
__global__ void k_quantF1(const float* __restrict__ w, const float* __restrict__ am,
                          unsigned short* __restrict__ wf) {
    float t = 0.05f * am[2];
    int i = blockIdx.x * 256 + threadIdx.x;    // 1048576, i = f*2048 + k
    int f = i >> 11, k = i & 2047;
    float v = w[i];
    unsigned short q = (v > t) ? (unsigned short)0x3F80
                     : ((v < -t) ? (unsigned short)0xBF80 : (unsigned short)0);
    int ft = f >> 4, fm = f & 15;
    int ks = k >> 5, kr = k & 31;
    int lane = (kr >> 3) * 16 + fm;
    wf[((size_t)(ks * 32 + ft) * 64 + lane) * 8 + (kr & 7)] = q;
}

// conv1 single pass: conv + fused bn1 stats + packed {max,min} per pool window.
__global__ __launch_bounds__(512) void k_conv1(const float* __restrict__ x,
                                               const float* __restrict__ w1t,
                                               unsigned* __restrict__ pmn1,
                                               float* __restrict__ sum,
                                               float* __restrict__ ssq) {
    __shared__ float xs[784];
    __shared__ float red[2][8][64];
    int b = blockIdx.x;
    const float4* xim = (const float4*)(x + (size_t)b * 784);
    for (int i = threadIdx.x; i < 196; i += 512) ((float4*)xs)[i] = xim[i];
    int c  = threadIdx.x & 63;
    int wv = threadIdx.x >> 6;
    float w[25];
    #pragma unroll
    for (int k = 0; k < 25; ++k) w[k] = w1t[k * 64 + c];
    __syncthreads();
    unsigned* ob = pmn1 + (size_t)b * 9216;
    float s = 0.f, s2 = 0.f;
    int ph = 0, pw = wv;
    for (int it = 0; it < 18; ++it) {
        const float* xp = xs + (ph * 2) * 28 + pw * 2;
        float win[36];
        #pragma unroll
        for (int i = 0; i < 6; ++i)
            #pragma unroll
            for (int j = 0; j < 3; ++j) {
                float2 t2 = *(const float2*)(xp + i * 28 + j * 2);
                win[i * 6 + j * 2] = t2.x; win[i * 6 + j * 2 + 1] = t2.y;
            }
        float v00 = 0.f, v01 = 0.f, v10 = 0.f, v11 = 0.f;
        #pragma unroll
        for (int i = 0; i < 5; ++i)
            #pragma unroll
            for (int j = 0; j < 5; ++j) {
                float wk = w[i * 5 + j];
                v00 = fmaf(win[i * 6 + j],           wk, v00);
                v01 = fmaf(win[i * 6 + j + 1],       wk, v01);
                v10 = fmaf(win[(i + 1) * 6 + j],     wk, v10);
                v11 = fmaf(win[(i + 1) * 6 + j + 1], wk, v11);
            }
        s  += v00 + v01 + v10 + v11;
        s2 += v00 * v00 + v01 * v01 + v10 * v10 + v11 * v11;
        float mx = fmaxf(fmaxf(v00, v01), fmaxf(v10, v11));
        float mn = fminf(fminf(v00, v01), fminf(v10, v11));
        ob[(ph * 12 + pw) * 64 + c] = ((unsigned)f2bf(mx) << 16) | (unsigned)f2bf(mn);
        pw += 8; if (pw >= 12) { pw -= 12; ++ph; }
    }
    red[0][wv][c] = s; red[1][wv][c] = s2;
    __syncthreads();
    if (threadIdx.x < 64) {
        float S = 0.f, S2 = 0.f;
        #pragma unroll
        for (int i = 0; i < 8; ++i) { S += red[0][i][threadIdx.x]; S2 += red[1][i][threadIdx.x]; }
        atomicAdd(&sum[threadIdx.x], S);
        atomicAdd(&ssq[threadIdx.x], S2);
    }
}

// bn1 (inline finalize) + relu + pool-select on packed pairs -> pool1 NHWC bf16
__global__ void k_bnpool1(const unsigned* __restrict__ pmn1,
                          const float* __restrict__ c1sum, const float* __restrict__ c1ssq,
                          const float* __restrict__ g1, const float* __restrict__ b1,
                          unsigned short* __restrict__ pool1) {
    int i = blockIdx.x * 256 + threadIdx.x;    // 4718592
    int c = i & 63;
    const float invN = 1.f / 294912.f;
    float mean = c1sum[c] * invN;
    float var  = c1ssq[c] * invN - mean * mean;
    float sc = g1[c] * rsqrtf(var + EPS);
    float sh = b1[c] - mean * sc;
    unsigned u = pmn1[i];
    float mx = __uint_as_float(u & 0xffff0000u);
    float mn = __uint_as_float(u << 16);
    float v = (sc > 0.f) ? mx : mn;
    pool1[i] = f2bf(fmaxf(0.f, fmaf(v, sc, sh)));
}

// conv2 MFMA v3.4: K-split waves. Block = (image, mhalf), grid 1024, 4 waves =
// (nh, kp). Per p (25 barriers): each wave 8 MFMAs (4 mt x 2 bf) from only
// 6 ds_read_b128 (4 af at its kp + 2 bf). Cross-kp merge via dead act-LDS.
__global__ __launch_bounds__(256) void k_conv2(const unsigned short* __restrict__ pool1,
                                               const unsigned short* __restrict__ wfrag,
                                               float* __restrict__ pmn,
                                               float* __restrict__ sum,
                                               float* __restrict__ ssq) {
    __shared__ unsigned short xs[144 * 76];    // 21888 B; reused as merge buf
    __shared__ unsigned short wb[2][4096];     // 2 x 8KB: one p = 2 ks x 4 mt
    __shared__ float reds[2][64], redq[2][64];
    int b     = blockIdx.x >> 1;
    int mhalf = blockIdx.x & 1;
    int tid  = threadIdx.x;
    int lane = tid & 63;
    int wave = tid >> 6;
    int nh = wave & 1, kp = wave >> 1;
    const unsigned short* src = pool1 + (size_t)b * 9216;
    for (int i = tid; i < 1152; i += 256) {
        int r = i >> 3, part = i & 7;
        *(float4*)(&xs[r * 76 + part * 8]) = *(const float4*)(src + r * 64 + part * 8);
    }
    // prefetch p=0: wave stages (ks,mt) pairs ksm = wave*2 + h
    #pragma unroll
    for (int h = 0; h < 2; ++h) {
        int ksm = wave * 2 + h;
        int ks = ksm >> 2, mt = ksm & 3;
        const unsigned short* g = wfrag + (size_t)(ks * 8 + mhalf * 4 + mt) * 512 + lane * 8;
        stage16(g, &wb[0][ks * 2048 + mt * 512 + lane * 8]);
    }
    __syncthreads();

    int n = lane & 15, quad = lane >> 4;
    int ow = n & 7;
    int ohb0 = nh * 4 + (n >> 3);              // oh of bf0; bf1 = +2
    int col0 = kp * 32 + quad * 8;
    v4f acc[4][2];
    #pragma unroll
    for (int mm = 0; mm < 4; ++mm) { acc[mm][0] = (v4f){0,0,0,0}; acc[mm][1] = (v4f){0,0,0,0}; }
    for (int p = 0; p < 25; ++p) {
        int cur = p & 1;
        if (p < 24) {
            #pragma unroll
            for (int h = 0; h < 2; ++h) {
                int ksm = wave * 2 + h;
                int ks = ksm >> 2, mt = ksm & 3;
                const unsigned short* g = wfrag +
                    (size_t)(((p + 1) * 2 + ks) * 8 + mhalf * 4 + mt) * 512 + lane * 8;
                stage16(g, &wb[cur ^ 1][ks * 2048 + mt * 512 + lane * 8]);
            }
        }
        int kh = p / 5, kw = p - (p / 5) * 5;
        int col = (ow + kw) * 76 + col0;
        v8s bf0 = *(const v8s*)(&xs[(ohb0 + kh) * 912 + col]);       // 12*76=912
        v8s bf1 = *(const v8s*)(&xs[(ohb0 + 2 + kh) * 912 + col]);
        #pragma unroll
        for (int mm = 0; mm < 4; ++mm) {
            v8s af = *(const v8s*)(&wb[cur][kp * 2048 + mm * 512 + lane * 8]);
            acc[mm][0] = __builtin_amdgcn_mfma_f32_16x16x32_bf16(af, bf0, acc[mm][0], 0, 0, 0);
            acc[mm][1] = __builtin_amdgcn_mfma_f32_16x16x32_bf16(af, bf1, acc[mm][1], 0, 0, 0);
        }
        __syncthreads();
    }
    // merge kp=1 partials into kp=0 via dead act-LDS (stride-36 float pad)
    float* mbuf = (float*)xs;                  // need 128*36*4 = 18432 B <= 21888
    if (kp == 1) {
        float* d = mbuf + (nh * 64 + lane) * 36;
        #pragma unroll
        for (int mm = 0; mm < 4; ++mm) {
            *(v4f*)(d + mm * 8)     = acc[mm][0];
            *(v4f*)(d + mm * 8 + 4) = acc[mm][1];
        }
    }
    __syncthreads();
    if (kp == 0) {
        const float* s = mbuf + (nh * 64 + lane) * 36;
        #pragma unroll
        for (int mm = 0; mm < 4; ++mm) {
            acc[mm][0] += *(const v4f*)(s + mm * 8);
            acc[mm][1] += *(const v4f*)(s + mm * 8 + 4);
        }
        // epilogue: pooled {max,min} + per-channel stats (64 ch within block)
        float* po = pmn + (size_t)b * 4096;    // [128][16][2]
        #pragma unroll
        for (int mm = 0; mm < 4; ++mm) {
            int cl0 = mm * 16 + quad * 4;
            #pragma unroll
            for (int r = 0; r < 4; ++r) {
                int cl = cl0 + r;
                int c  = mhalf * 64 + cl;
                float sA = 0.f, s2A = 0.f;
                #pragma unroll
                for (int bf = 0; bf < 2; ++bf) {
                    float v = acc[mm][bf][r];
                    float pm = fmaxf(v, __shfl_xor(v, 1));
                    float pn = fminf(v, __shfl_xor(v, 1));
                    pm = fmaxf(pm, __shfl_xor(pm, 8));
                    pn = fminf(pn, __shfl_xor(pn, 8));
                    if (((n & 1) == 0) && (n < 8)) {
                        int psp = (nh * 2 + bf) * 4 + (n >> 1);
                        *(float2*)(&po[(c * 16 + psp) * 2]) = make_float2(pm, pn);
                    }
                    float s = v, s2 = v * v;
                    #pragma unroll
                    for (int m = 1; m < 16; m <<= 1) { s += __shfl_xor(s, m); s2 += __shfl_xor(s2, m); }
                    sA += s; s2A += s2;
                }
                if (n == 0) { reds[nh][cl] = sA; redq[nh][cl] = s2A; }
            }
        }
    }
    __syncthreads();
    if (tid < 64) {
        atomicAdd(&sum[mhalf * 64 + tid], reds[0][tid] + reds[1][tid]);
        atomicAdd(&ssq[mhalf * 64 + tid], redq[0][tid] + redq[1][tid]);
    }
}

// bn2 finalize inline + relu on pooled pairs -> pool2 bf16 in fc1 B-frag order
__global__ void k_bnpool2(const float* __restrict__ pmn, const float* __restrict__ c2sum,
                          const float* __restrict__ c2ssq, const float* __restrict__ g2,
                          const float* __restrict__ b2, unsigned short* __restrict__ xfrag) {
    int i = blockIdx.x * 256 + threadIdx.x;    // 1048576
    int j    = i & 7;
    int lane = (i >> 3) & 63;
    int bt   = (i >> 9) & 31;
    int ks   = i >> 14;
    int b = bt * 16 + (lane & 15);
    int k = ks * 32 + (lane >> 4) * 8 + j;
    int c = k >> 4, psp = k & 15;
    float2 mm = *(const float2*)(&pmn[((size_t)b * 2048 + c * 16 + psp) * 2]);
    float mean = c2sum[c] * (1.f / 32768.f);
    float var  = c2ssq[c] * (1.f / 32768.f) - mean * mean;
    float sc = g2[c] * rsqrtf(var + EPS);
    float sh = b2[c] - mean * sc;
    float v = (sc > 0.f) ? mm.x : mm.y;
    xfrag[i] = f2bf(fmaxf(0.f, fmaf(v, sc, sh)));
}

// fc1 MFMA: grid 256 (full CU coverage), wave = 1 f-tile; fused bn3 stats.
__global__ __launch_bounds__(256) void k_fc1(const unsigned short* __restrict__ xfrag,
                                             const unsigned short* __restrict__ wfrag,
                                             float* __restrict__ out,
                                             float* __restrict__ sum,
                                             float* __restrict__ ssq) {
    int lane = threadIdx.x & 63;
    int wave = threadIdx.x >> 6;
    int ft = (blockIdx.x & 7) * 4 + wave;      // f-tile 0..31
    int bT = blockIdx.x >> 3;                  // 0..31
    v4f acc = (v4f){0.f, 0.f, 0.f, 0.f};
    for (int ks = 0; ks < 64; ++ks) {
        v8s bfrag = *(const v8s*)(xfrag + ((size_t)(ks * 32 + bT) * 64 + lane) * 8);
        v8s afrag = *(const v8s*)(wfrag + ((size_t)(ks * 32 + ft) * 64 + lane) * 8);
        acc = __builtin_amdgcn_mfma_f32_16x16x32_bf16(afrag, bfrag, acc, 0, 0, 0);
    }
    int bb = bT * 16 + (lane & 15);
    int quad = lane >> 4;
    int f0 = ft * 16 + quad * 4;
    *(float4*)(&out[(size_t)bb * 512 + f0]) =
        make_float4(acc[0], acc[1], acc[2], acc[3]);
    #pragma unroll
    for (int r = 0; r < 4; ++r) {
        float s = acc[r], s2 = s * s;
        #pragma unroll
        for (int m = 1; m < 16; m <<= 1) { s += __shfl_xor(s, m); s2 += __shfl_xor(s2, m); }
        if ((lane & 15) == 0) { atomicAdd(&sum[f0 + r], s); atomicAdd(&ssq[f0 + r], s2); }
    }
}

// fc2 with inline bn3 finalize + relu: wave per batch row.
__global__ __launch_bounds__(256) void k_fc2(const float* __restrict__ x,
                                             const float* __restrict__ w,
                                             const float* __restrict__ bias,
                                             const float* __restrict__ fsum,
                                             const float* __restrict__ fssq,
                                             const float* __restrict__ g3,
                                             const float* __restrict__ b3,
                                             float* __restrict__ out) {
    int lane = threadIdx.x & 63;
    int b = blockIdx.x * 4 + (threadIdx.x >> 6);
    float xa[8], sm[8], sq[8], ga[8], ba[8];
    {
        const float4* p;
        p = (const float4*)(x + (size_t)b * 512 + lane * 8);
        *(float4*)xa = p[0]; *(float4*)(xa + 4) = p[1];
        p = (const float4*)(fsum + lane * 8);
        *(float4*)sm = p[0]; *(float4*)(sm + 4) = p[1];
        p = (const float4*)(fssq + lane * 8);
        *(float4*)sq = p[0]; *(float4*)(sq + 4) = p[1];
        p = (const float4*)(g3 + lane * 8);
        *(float4*)ga = p[0]; *(float4*)(ga + 4) = p[1];
        p = (const float4*)(b3 + lane * 8);
        *(float4*)ba = p[0]; *(float4*)(ba + 4) = p[1];
    }
    float h[8];
    #pragma unroll
    for (int e = 0; e < 8; ++e) {
        float mean = sm[e] * (1.f / 512.f);
        float var  = sq[e] * (1.f / 512.f) - mean * mean;
        float sc = ga[e] * rsqrtf(var + EPS);
        float sh = ba[e] - mean * sc;
        h[e] = fmaxf(0.f, fmaf(xa[e], sc, sh));
    }
    #pragma unroll
    for (int j = 0; j < 10; ++j) {
        const float4* wp = (const float4*)(w + j * 512 + lane * 8);
        float4 w0 = wp[0], w1 = wp[1];
        float p = h[0] * w0.x + h[1] * w0.y + h[2] * w0.z + h[3] * w0.w
                + h[4] * w1.x + h[5] * w1.y + h[6] * w1.z + h[7] * w1.w;
        #pragma unroll
        for (int o = 32; o; o >>= 1) p += __shfl_down(p, o);
        if (lane == 0) out[b * 10 + j] = p + bias[j];
    }
}

extern "C" void kernel_launch(void* const* d_in, const int* in_sizes, int n_in,
                              void* d_out, int out_size, void* d_ws, size_t ws_size,
                              hipStream_t stream) {
    const float* x       = (const float*)d_in[0];
    const float* conv1_w = (const float*)d_in[1];
    const float* bn1_g   = (const float*)d_in[3];
    const float* bn1_b   = (const float*)d_in[4];
    const float* conv2_w = (const float*)d_in[5];
    const float* bn2_g   = (const float*)d_in[7];
    const float* bn2_b   = (const float*)d_in[8];
    const float* fc1_w   = (const float*)d_in[9];
    const float* bn3_g   = (const float*)d_in[11];
    const float* bn3_b   = (const float*)d_in[12];
    const float* fc2_w   = (const float*)d_in[13];
    const float* fc2_b   = (const float*)d_in[14];
    // conv1_b / conv2_b / fc1_b are absorbed by train-mode BN

    float* wsf = (float*)d_ws;

    float* c1_sum = wsf + 16,   * c1_ssq = wsf + 80;
    float* c2_sum = wsf + 272,  * c2_ssq = wsf + 400;
    float* f_sum  = wsf + 1808, * f_ssq  = wsf + 2320;

    float* w1t = wsf + W1F;
    unsigned short* w2u = (unsigned short*)(wsf + W2F);
    float* wf2 = wsf + WF2F;
    unsigned short* wf1 = (unsigned short*)(wsf + WF1T);
    unsigned* PMN1 = (unsigned*)(wsf + A_F);         // [512][144][64] packed
    float* PMN2 = wsf + A_F;                         // [512][128][16][2]
    float* A    = wsf + A_F;                         // fc1out
    unsigned short* pool1 = (unsigned short*)(wsf + B_F);
    unsigned short* xfrag = (unsigned short*)(wsf + B_F);

    // zero stats (absmax + sums)
    k_zero<<<16, 256, 0, stream>>>(wsf, 4096);

    // absmax (all 4 tensors)
    k_absmax4<<<210, 256, 0, stream>>>(conv1_w, 1600, conv2_w, 204800,
                                       fc1_w, 1048576, fc2_w, 5120, wsf);

    // quantize conv1 / conv2 (MFMA-frag bf16) / fc2
    k_quantE<<<102, 256, 0, stream>>>(conv1_w, conv2_w, fc2_w, wsf, w1t, w2u, wf2);

    // conv1 single pass: stats + packed {max,min} -> PMN1
    k_conv1<<<512, 512, 0, stream>>>(x, w1t, PMN1, c1_sum, c1_ssq);

    // bn1 finalize + relu + pool-select -> pool1 NHWC bf16
    k_bnpool1<<<18432, 256, 0, stream>>>(PMN1, c1_sum, c1_ssq, bn1_g, bn1_b, pool1);

    // conv2 MFMA v3.4 (K-split waves) -> PMN2 + bn2 stats
    k_conv2<<<1024, 256, 0, stream>>>(pool1, w2u, PMN2, c2_sum, c2_ssq);

    // fc1 weights -> bf16 A-frag (pool1 now dead)
    k_quantF1<<<4096, 256, 0, stream>>>(fc1_w, wsf, wf1);

    // bn2 (inline finalize) + relu on pooled pairs -> pool2 bf16 B-frag
    k_bnpool2<<<4096, 256, 0, stream>>>(PMN2, c2_sum, c2_ssq, bn2_g, bn2_b, xfrag);

    // fc1 MFMA (grid 256, fused bn3 stats) -> A fp32 [512,512]
    k_fc1<<<256, 256, 0, stream>>>(xfrag, wf1, A, f_sum, f_ssq);

    // fc2 (inline bn3 finalize + relu) -> d_out [512,10]
    k_fc2<<<128, 256, 0, stream>>>(A, wf2, fc2_b, f_sum, f_ssq, bn3_g, bn3_b,
                                   (float*)d_out);
}

// Round 15
// 208.468 us; speedup vs baseline: 2.6001x; 1.0272x over previous
//
#include <hip/hip_runtime.h>
#include <stdint.h>

#define EPS 1e-5f

typedef short v8s __attribute__((ext_vector_type(8)));
typedef float v4f __attribute__((ext_vector_type(4)));

// ---------------- ws float layout (round-13 exact) ----------------
//  [0,4)     absmax {c1,c2,f1,f2}
//  16/80    c1 sum/ssq (64 each)
//  272/400  c2 sum/ssq (128 each)
//  1808 fc sum(512) 2320 fc ssq(512)
//  W1F  = 4096    : conv1 weights float [k=25][c=64]
//  W2F  = 8192    : conv2 weights bf16 MFMA-frag order (204800 us)
//  WF2F = 212992  : fc2 weights float [j][512]
//  A_F  = 262144  : pmn1 packed uint [512][144][64]; later PMN2 fp32
//                   [512][128][16][2]; later fc1out fp32 [512,512]
//  B_F  = 19136512: pool1 bf16 NHWC [512][144][64]; later pool2 bf16 B-frag
//  WF1T = B_F + 1048576 : fc1 weights bf16 A-frag (written after conv2)
static const size_t W1F  = 4096;
static const size_t W2F  = 8192;
static const size_t WF2F = 212992;
static const size_t A_F  = 262144;
static const size_t B_F  = 19136512;
static const size_t WF1T = B_F + 1048576;

__device__ inline unsigned short f2bf(float f) {
    unsigned u = __float_as_uint(f);
    return (unsigned short)((u + 0x7FFF + ((u >> 16) & 1)) >> 16);
}

// async global->LDS, 16B per lane
__device__ __forceinline__ void stage16(const unsigned short* g, unsigned short* l) {
    __builtin_amdgcn_global_load_lds(
        (const __attribute__((address_space(1))) unsigned int*)g,
        (__attribute__((address_space(3))) unsigned int*)l, 16, 0, 0);
}

__global__ void k_zero(float* p, int n) {
    int i = blockIdx.x * blockDim.x + threadIdx.x;
    if (i < n) p[i] = 0.f;
}

// 4 absmax reductions in one launch
__global__ void k_absmax4(const float* __restrict__ w0, int n0,
                          const float* __restrict__ w1, int n1,
                          const float* __restrict__ w2, int n2,
                          const float* __restrict__ w3, int n3,
                          float* outv) {
    int blk = blockIdx.x;
    const float* w; int n; unsigned* out; int nb; int bi;
    if (blk < 1)        { w = w0; n = n0; out = (unsigned*)(outv + 0); nb = 1;   bi = blk;      }
    else if (blk < 17)  { w = w1; n = n1; out = (unsigned*)(outv + 1); nb = 16;  bi = blk - 1;  }
    else if (blk < 209) { w = w2; n = n2; out = (unsigned*)(outv + 2); nb = 192; bi = blk - 17; }
    else                { w = w3; n = n3; out = (unsigned*)(outv + 3); nb = 1;   bi = blk - 209; }
    float m = 0.f;
    for (int i = bi * 256 + threadIdx.x; i < n; i += nb * 256)
        m = fmaxf(m, fabsf(w[i]));
    #pragma unroll
    for (int o = 32; o; o >>= 1) m = fmaxf(m, __shfl_down(m, o));
    if ((threadIdx.x & 63) == 0) atomicMax(out, __float_as_uint(m));
}

// quantize: conv1 -> w1t float [k=25][c=64]; conv2 -> bf16 A-frag order; fc2 float.
// grid 402: blk0 conv1; blk 1..400 conv2 (512 elems each); blk 401 fc2.
// conv2 frag: idx = ((p*2+ks)*8 + mt)*512 + lane*8 + j
//   = Q(conv2_w[c][ci][p]), c = mt*16 + (lane&15), ci = ks*32 + (lane>>4)*8 + j
__global__ void k_quantE(const float* __restrict__ c1w, const float* __restrict__ c2w,
                         const float* __restrict__ f2w, const float* __restrict__ am,
                         float* __restrict__ w1t, unsigned short* __restrict__ w2u,
                         float* __restrict__ wf2) {
    int blk = blockIdx.x;
    if (blk < 1) {
        float t = 0.05f * am[0];
        for (int i = threadIdx.x; i < 1600; i += 256) {
            float v = c1w[i];
            float q = (float)((v > t) - (v < -t));
            int c = i / 25, k = i - c * 25;
            w1t[k * 64 + c] = q;
        }
    } else if (blk < 401) {
        float t = 0.05f * am[1];
        int base = (blk - 1) * 512;
        #pragma unroll
        for (int jj = 0; jj < 2; ++jj) {
            int i = base + jj * 256 + threadIdx.x;
            int j    = i & 7;
            int lane = (i >> 3) & 63;
            int mt   = (i >> 9) & 7;
            int ks   = (i >> 12) & 1;
            int p    = i >> 13;
            int c  = mt * 16 + (lane & 15);
            int ci = ks * 32 + (lane >> 4) * 8 + j;
            float v = c2w[c * 1600 + ci * 25 + p];
            w2u[i] = (v > t) ? (unsigned short)0x3F80
                             : ((v < -t) ? (unsigned short)0xBF80 : (unsigned short)0);
        }
    } else {
        float t = 0.05f * am[3];
        for (int i = threadIdx.x; i < 5120; i += 256) {
            float v = f2w[i];
            wf2[i] = (float)((v > t) - (v < -t));
        }
    }
}

// conv1 single pass: conv + fused bn1 stats + packed {max,min} per pool window.
__global__ __launch_bounds__(512) void k_conv1(const float* __restrict__ x,
                                               const float* __restrict__ w1t,
                                               unsigned* __restrict__ pmn1,
                                               float* __restrict__ sum,
                                               float* __restrict__ ssq) {
    __shared__ float xs[784];
    __shared__ float red[2][8][64];
    int b = blockIdx.x;
    const float4* xim = (const float4*)(x + (size_t)b * 784);
    for (int i = threadIdx.x; i < 196; i += 512) ((float4*)xs)[i] = xim[i];
    int c  = threadIdx.x & 63;
    int wv = threadIdx.x >> 6;
    float w[25];
    #pragma unroll
    for (int k = 0; k < 25; ++k) w[k] = w1t[k * 64 + c];
    __syncthreads();
    unsigned* ob = pmn1 + (size_t)b * 9216;
    float s = 0.f, s2 = 0.f;
    int ph = 0, pw = wv;
    for (int it = 0; it < 18; ++it) {
        const float* xp = xs + (ph * 2) * 28 + pw * 2;
        float win[36];
        #pragma unroll
        for (int i = 0; i < 6; ++i)
            #pragma unroll
            for (int j = 0; j < 3; ++j) {
                float2 t2 = *(const float2*)(xp + i * 28 + j * 2);
                win[i * 6 + j * 2] = t2.x; win[i * 6 + j * 2 + 1] = t2.y;
            }
        float v00 = 0.f, v01 = 0.f, v10 = 0.f, v11 = 0.f;
        #pragma unroll
        for (int i = 0; i < 5; ++i)
            #pragma unroll
            for (int j = 0; j < 5; ++j) {
                float wk = w[i * 5 + j];
                v00 = fmaf(win[i * 6 + j],           wk, v00);
                v01 = fmaf(win[i * 6 + j + 1],       wk, v01);
                v10 = fmaf(win[(i + 1) * 6 + j],     wk, v10);
                v11 = fmaf(win[(i + 1) * 6 + j + 1], wk, v11);
            }
        s  += v00 + v01 + v10 + v11;
        s2 += v00 * v00 + v01 * v01 + v10 * v10 + v11 * v11;
        float mx = fmaxf(fmaxf(v00, v01), fmaxf(v10, v11));
        float mn = fminf(fminf(v00, v01), fminf(v10, v11));
        ob[(ph * 12 + pw) * 64 + c] = ((unsigned)f2bf(mx) << 16) | (unsigned)f2bf(mn);
        pw += 8; if (pw >= 12) { pw -= 12; ++ph; }
    }
    red[0][wv][c] = s; red[1][wv][c] = s2;
    __syncthreads();
    if (threadIdx.x < 64) {
        float S = 0.f, S2 = 0.f;
        #pragma unroll
        for (int i = 0; i < 8; ++i) { S += red[0][i][threadIdx.x]; S2 += red[1][i][threadIdx.x]; }
        atomicAdd(&sum[threadIdx.x], S);
        atomicAdd(&ssq[threadIdx.x], S2);
    }
}

// bn1 (inline finalize) + relu + pool-select on packed pairs -> pool1 NHWC bf16
__global__ void k_bnpool1(const unsigned* __restrict__ pmn1,
                          const float* __restrict__ c1sum, const float* __restrict__ c1ssq,
                          const float* __restrict__ g1, const float* __restrict__ b1,
                          unsigned short* __restrict__ pool1) {
    int i = blockIdx.x * 256 + threadIdx.x;    // 4718592
    int c = i & 63;
    const float invN = 1.f / 294912.f;
    float mean = c1sum[c] * invN;
    float var  = c1ssq[c] * invN - mean * mean;
    float sc = g1[c] * rsqrtf(var + EPS);
    float sh = b1[c] - mean * sc;
    unsigned u = pmn1[i];
    float mx = __uint_as_float(u & 0xffff0000u);
    float mn = __uint_as_float(u << 16);
    float v = (sc > 0.f) ? mx : mn;
    pool1[i] = f2bf(fmaxf(0.f, fmaf(v, sc, sh)));
}

// conv2 MFMA v3.4 (round-13 exact, passing): K-split waves. Block = (image,
// mhalf), grid 1024, 4 waves = (nh, kp). Per p (25 barriers): 8 MFMAs from
// 6 ds_read_b128 per wave. Cross-kp merge via dead act-LDS.
__global__ __launch_bounds__(256) void k_conv2(const unsigned short* __restrict__ pool1,
                                               const unsigned short* __restrict__ wfrag,
                                               float* __restrict__ pmn,
                                               float* __restrict__ sum,
                                               float* __restrict__ ssq) {
    __shared__ unsigned short xs[144 * 76];    // 21888 B; reused as merge buf
    __shared__ unsigned short wb[2][4096];     // 2 x 8KB: one p = 2 ks x 4 mt
    __shared__ float reds[2][64], redq[2][64];
    int b     = blockIdx.x >> 1;
    int mhalf = blockIdx.x & 1;
    int tid  = threadIdx.x;
    int lane = tid & 63;
    int wave = tid >> 6;
    int nh = wave & 1, kp = wave >> 1;
    const unsigned short* src = pool1 + (size_t)b * 9216;
    for (int i = tid; i < 1152; i += 256) {
        int r = i >> 3, part = i & 7;
        *(float4*)(&xs[r * 76 + part * 8]) = *(const float4*)(src + r * 64 + part * 8);
    }
    // prefetch p=0: wave stages (ks,mt) pairs ksm = wave*2 + h
    #pragma unroll
    for (int h = 0; h < 2; ++h) {
        int ksm = wave * 2 + h;
        int ks = ksm >> 2, mt = ksm & 3;
        const unsigned short* g = wfrag + (size_t)(ks * 8 + mhalf * 4 + mt) * 512 + lane * 8;
        stage16(g, &wb[0][ks * 2048 + mt * 512 + lane * 8]);
    }
    __syncthreads();

    int n = lane & 15, quad = lane >> 4;
    int ow = n & 7;
    int ohb0 = nh * 4 + (n >> 3);              // oh of bf0; bf1 = +2
    int col0 = kp * 32 + quad * 8;
    v4f acc[4][2];
    #pragma unroll
    for (int mm = 0; mm < 4; ++mm) { acc[mm][0] = (v4f){0,0,0,0}; acc[mm][1] = (v4f){0,0,0,0}; }
    for (int p = 0; p < 25; ++p) {
        int cur = p & 1;
        if (p < 24) {
            #pragma unroll
            for (int h = 0; h < 2; ++h) {
                int ksm = wave * 2 + h;
                int ks = ksm >> 2, mt = ksm & 3;
                const unsigned short* g = wfrag +
                    (size_t)(((p + 1) * 2 + ks) * 8 + mhalf * 4 + mt) * 512 + lane * 8;
                stage16(g, &wb[cur ^ 1][ks * 2048 + mt * 512 + lane * 8]);
            }
        }
        int kh = p / 5, kw = p - (p / 5) * 5;
        int col = (ow + kw) * 76 + col0;
        v8s bf0 = *(const v8s*)(&xs[(ohb0 + kh) * 912 + col]);       // 12*76=912
        v8s bf1 = *(const v8s*)(&xs[(ohb0 + 2 + kh) * 912 + col]);
        #pragma unroll
        for (int mm = 0; mm < 4; ++mm) {
            v8s af = *(const v8s*)(&wb[cur][kp * 2048 + mm * 512 + lane * 8]);
            acc[mm][0] = __builtin_amdgcn_mfma_f32_16x16x32_bf16(af, bf0, acc[mm][0], 0, 0, 0);
            acc[mm][1] = __builtin_amdgcn_mfma_f32_16x16x32_bf16(af, bf1, acc[mm][1], 0, 0, 0);
        }
        __syncthreads();
    }
    // merge kp=1 partials into kp=0 via dead act-LDS (stride-36 float pad)
    float* mbuf = (float*)xs;                  // 128*36*4 = 18432 B <= 21888
    if (kp == 1) {
        float* d = mbuf + (nh * 64 + lane) * 36;
        #pragma unroll
        for (int mm = 0; mm < 4; ++mm) {
            *(v4f*)(d + mm * 8)     = acc[mm][0];
            *(v4f*)(d + mm * 8 + 4) = acc[mm][1];
        }
    }
    __syncthreads();
    if (kp == 0) {
        const float* s = mbuf + (nh * 64 + lane) * 36;
        #pragma unroll
        for (int mm = 0; mm < 4; ++mm) {
            acc[mm][0] += *(const v4f*)(s + mm * 8);
            acc[mm][1] += *(const v4f*)(s + mm * 8 + 4);
        }
        // epilogue: pooled {max,min} + per-channel stats (64 ch within block)
        float* po = pmn + (size_t)b * 4096;    // [128][16][2]
        #pragma unroll
        for (int mm = 0; mm < 4; ++mm) {
            int cl0 = mm * 16 + quad * 4;
            #pragma unroll
            for (int r = 0; r < 4; ++r) {
                int cl = cl0 + r;
                int c  = mhalf * 64 + cl;
                float sA = 0.f, s2A = 0.f;
                #pragma unroll
                for (int bf = 0; bf < 2; ++bf) {
                    float v = acc[mm][bf][r];
                    float pm = fmaxf(v, __shfl_xor(v, 1));
                    float pn = fminf(v, __shfl_xor(v, 1));
                    pm = fmaxf(pm, __shfl_xor(pm, 8));
                    pn = fminf(pn, __shfl_xor(pn, 8));
                    if (((n & 1) == 0) && (n < 8)) {
                        int psp = (nh * 2 + bf) * 4 + (n >> 1);
                        *(float2*)(&po[(c * 16 + psp) * 2]) = make_float2(pm, pn);
                    }
                    float s = v, s2 = v * v;
                    #pragma unroll
                    for (int m = 1; m < 16; m <<= 1) { s += __shfl_xor(s, m); s2 += __shfl_xor(s2, m); }
                    sA += s; s2A += s2;
                }
                if (n == 0) { reds[nh][cl] = sA; redq[nh][cl] = s2A; }
            }
        }
    }
    __syncthreads();
    if (tid < 64) {
        atomicAdd(&sum[mhalf * 64 + tid], reds[0][tid] + reds[1][tid]);
        atomicAdd(&ssq[mhalf * 64 + tid], redq[0][tid] + redq[1][tid]);
    }
}

// merged: quantF1 (blk < 4096) + bnpool2 (blk >= 4096); runs AFTER conv2
__global__ void k_prep_fc1(const float* __restrict__ w, const float* __restrict__ am,
                           unsigned short* __restrict__ wf,
                           const float* __restrict__ pmn2, const float* __restrict__ c2sum,
                           const float* __restrict__ c2ssq, const float* __restrict__ g2,
                           const float* __restrict__ b2, unsigned short* __restrict__ xfrag) {
    if (blockIdx.x < 4096) {
        // fc1 quantize, f-major coalesced read -> bf16 A-frag scatter write
        float t = 0.05f * am[2];
        int i = blockIdx.x * 256 + threadIdx.x;    // i = f*2048 + k
        int f = i >> 11, k = i & 2047;
        float v = w[i];
        unsigned short q = (v > t) ? (unsigned short)0x3F80
                         : ((v < -t) ? (unsigned short)0xBF80 : (unsigned short)0);
        int ft = f >> 4, fm = f & 15;
        int ks = k >> 5, kr = k & 31;
        int lane = (kr >> 3) * 16 + fm;
        wf[((size_t)(ks * 32 + ft) * 64 + lane) * 8 + (kr & 7)] = q;
    } else {
        int i = (blockIdx.x - 4096) * 256 + threadIdx.x;   // 1048576
        int j    = i & 7;
        int lane = (i >> 3) & 63;
        int bt   = (i >> 9) & 31;
        int ks   = i >> 14;
        int b = bt * 16 + (lane & 15);
        int k = ks * 32 + (lane >> 4) * 8 + j;
        int c = k >> 4, psp = k & 15;
        float2 mm = *(const float2*)(&pmn2[((size_t)b * 2048 + c * 16 + psp) * 2]);
        float mean = c2sum[c] * (1.f / 32768.f);
        float var  = c2ssq[c] * (1.f / 32768.f) - mean * mean;
        float sc = g2[c] * rsqrtf(var + EPS);
        float sh = b2[c] - mean * sc;
        float v = (sc > 0.f) ? mm.x : mm.y;
        xfrag[i] = f2bf(fmaxf(0.f, fmaf(v, sc, sh)));
    }
}

// fc1 MFMA: grid 256, wave = 1 f-tile; fused bn3 stats.
__global__ __launch_bounds__(256) void k_fc1(const unsigned short* __restrict__ xfrag,
                                             const unsigned short* __restrict__ wfrag,
                                             float* __restrict__ out,
                                             float* __restrict__ sum,
                                             float* __restrict__ ssq) {
    int lane = threadIdx.x & 63;
    int wave = threadIdx.x >> 6;
    int ft = (blockIdx.x & 7) * 4 + wave;      // f-tile 0..31
    int bT = blockIdx.x >> 3;                  // 0..31
    v4f acc = (v4f){0.f, 0.f, 0.f, 0.f};
    for (int ks = 0; ks < 64; ++ks) {
        v8s bfrag = *(const v8s*)(xfrag + ((size_t)(ks * 32 + bT) * 64 + lane) * 8);
        v8s afrag = *(const v8s*)(wfrag + ((size_t)(ks * 32 + ft) * 64 + lane) * 8);
        acc = __builtin_amdgcn_mfma_f32_16x16x32_bf16(afrag, bfrag, acc, 0, 0, 0);
    }
    int bb = bT * 16 + (lane & 15);
    int quad = lane >> 4;
    int f0 = ft * 16 + quad * 4;
    *(float4*)(&out[(size_t)bb * 512 + f0]) =
        make_float4(acc[0], acc[1], acc[2], acc[3]);
    #pragma unroll
    for (int r = 0; r < 4; ++r) {
        float s = acc[r], s2 = s * s;
        #pragma unroll
        for (int m = 1; m < 16; m <<= 1) { s += __shfl_xor(s, m); s2 += __shfl_xor(s2, m); }
        if ((lane & 15) == 0) { atomicAdd(&sum[f0 + r], s); atomicAdd(&ssq[f0 + r], s2); }
    }
}

// fc2 with inline bn3 finalize + relu: wave per batch row.
__global__ __launch_bounds__(256) void k_fc2(const float* __restrict__ x,
                                             const float* __restrict__ w,
                                             const float* __restrict__ bias,
                                             const float* __restrict__ fsum,
                                             const float* __restrict__ fssq,
                                             const float* __restrict__ g3,
                                             const float* __restrict__ b3,
                                             float* __restrict__ out) {
    int lane = threadIdx.x & 63;
    int b = blockIdx.x * 4 + (threadIdx.x >> 6);
    float xa[8], sm[8], sq[8], ga[8], ba[8];
    {
        const float4* p;
        p = (const float4*)(x + (size_t)b * 512 + lane * 8);
        *(float4*)xa = p[0]; *(float4*)(xa + 4) = p[1];
        p = (const float4*)(fsum + lane * 8);
        *(float4*)sm = p[0]; *(float4*)(sm + 4) = p[1];
        p = (const float4*)(fssq + lane * 8);
        *(float4*)sq = p[0]; *(float4*)(sq + 4) = p[1];
        p = (const float4*)(g3 + lane * 8);
        *(float4*)ga = p[0]; *(float4*)(ga + 4) = p[1];
        p = (const float4*)(b3 + lane * 8);
        *(float4*)ba = p[0]; *(float4*)(ba + 4) = p[1];
    }
    float h[8];
    #pragma unroll
    for (int e = 0; e < 8; ++e) {
        float mean = sm[e] * (1.f / 512.f);
        float var  = sq[e] * (1.f / 512.f) - mean * mean;
        float sc = ga[e] * rsqrtf(var + EPS);
        float sh = ba[e] - mean * sc;
        h[e] = fmaxf(0.f, fmaf(xa[e], sc, sh));
    }
    #pragma unroll
    for (int j = 0; j < 10; ++j) {
        const float4* wp = (const float4*)(w + j * 512 + lane * 8);
        float4 w0 = wp[0], w1 = wp[1];
        float p = h[0] * w0.x + h[1] * w0.y + h[2] * w0.z + h[3] * w0.w
                + h[4] * w1.x + h[5] * w1.y + h[6] * w1.z + h[7] * w1.w;
        #pragma unroll
        for (int o = 32; o; o >>= 1) p += __shfl_down(p, o);
        if (lane == 0) out[b * 10 + j] = p + bias[j];
    }
}

extern "C" void kernel_launch(void* const* d_in, const int* in_sizes, int n_in,
                              void* d_out, int out_size, void* d_ws, size_t ws_size,
                              hipStream_t stream) {
    const float* x       = (const float*)d_in[0];
    const float* conv1_w = (const float*)d_in[1];
    const float* bn1_g   = (const float*)d_in[3];
    const float* bn1_b   = (const float*)d_in[4];
    const float* conv2_w = (const float*)d_in[5];
    const float* bn2_g   = (const float*)d_in[7];
    const float* bn2_b   = (const float*)d_in[8];
    const float* fc1_w   = (const float*)d_in[9];
    const float* bn3_g   = (const float*)d_in[11];
    const float* bn3_b   = (const float*)d_in[12];
    const float* fc2_w   = (const float*)d_in[13];
    const float* fc2_b   = (const float*)d_in[14];
    // conv1_b / conv2_b / fc1_b are absorbed by train-mode BN

    float* wsf = (float*)d_ws;

    float* c1_sum = wsf + 16,   * c1_ssq = wsf + 80;
    float* c2_sum = wsf + 272,  * c2_ssq = wsf + 400;
    float* f_sum  = wsf + 1808, * f_ssq  = wsf + 2320;

    float* w1t = wsf + W1F;
    unsigned short* w2u = (unsigned short*)(wsf + W2F);
    float* wf2 = wsf + WF2F;
    unsigned short* wf1 = (unsigned short*)(wsf + WF1T);
    unsigned* PMN1 = (unsigned*)(wsf + A_F);         // [512][144][64] packed
    float* PMN2 = wsf + A_F;                         // [512][128][16][2] (pmn1 dead)
    float* A    = wsf + A_F;                         // fc1out (PMN2 dead by then)
    unsigned short* pool1 = (unsigned short*)(wsf + B_F);
    unsigned short* xfrag = (unsigned short*)(wsf + B_F);

    // zero stats (absmax + sums)
    k_zero<<<16, 256, 0, stream>>>(wsf, 4096);

    // absmax (all 4 tensors)
    k_absmax4<<<210, 256, 0, stream>>>(conv1_w, 1600, conv2_w, 204800,
                                       fc1_w, 1048576, fc2_w, 5120, wsf);

    // quantize conv1 / conv2 (MFMA-frag bf16) / fc2 — 402 blocks
    k_quantE<<<402, 256, 0, stream>>>(conv1_w, conv2_w, fc2_w, wsf, w1t, w2u, wf2);

    // conv1 single pass: stats + packed {max,min} -> PMN1
    k_conv1<<<512, 512, 0, stream>>>(x, w1t, PMN1, c1_sum, c1_ssq);

    // bn1 finalize + relu + pool-select -> pool1 NHWC bf16
    k_bnpool1<<<18432, 256, 0, stream>>>(PMN1, c1_sum, c1_ssq, bn1_g, bn1_b, pool1);

    // conv2 MFMA v3.4 (round-13 exact) -> PMN2 + bn2 stats
    k_conv2<<<1024, 256, 0, stream>>>(pool1, w2u, PMN2, c2_sum, c2_ssq);

    // merged quantF1 + bnpool2 (pool1 dead after conv2)
    k_prep_fc1<<<8192, 256, 0, stream>>>(fc1_w, wsf, wf1, PMN2, c2_sum, c2_ssq,
                                         bn2_g, bn2_b, xfrag);

    // fc1 MFMA (grid 256, fused bn3 stats) -> A fp32 [512,512]
    k_fc1<<<256, 256, 0, stream>>>(xfrag, wf1, A, f_sum, f_ssq);

    // fc2 (inline bn3 finalize + relu) -> d_out [512,10]
    k_fc2<<<128, 256, 0, stream>>>(A, wf2, fc2_b, f_sum, f_ssq, bn3_g, bn3_b,
                                   (float*)d_out);
}